// Round 2
// baseline (1235.725 us; speedup 1.0000x reference)
//
#include <hip/hip_runtime.h>
#include <math.h>

// T5-style attention block, f32 baseline (round 1 resubmit: correctness + profile anchor).
// Pipeline: [qkv GEMM] -> [flash attn + rel-pos bias] -> [out GEMM].
// ws layout (floats): q[BH][S][D] | k[BH][S][D] | v[BH][S][D] | ctx[B][S][E]
// = 4 * 4,194,304 floats = 67.1 MB.

#define SEQ 2048
#define EMB 1024
#define NH 16
#define HD 64
#define NB 2
#define NBH 32

__global__ __launch_bounds__(256) void qkv_gemm_kernel(
    const float* __restrict__ hs,
    const float* __restrict__ Wq, const float* __restrict__ bq,
    const float* __restrict__ Wk, const float* __restrict__ bk,
    const float* __restrict__ Wv, const float* __restrict__ bv,
    float* __restrict__ ws) {
  __shared__ float As[16][68];  // [k][m], padded: transpose-write conflict-free-ish
  __shared__ float Bs[16][64];  // [k][n]
  const int t  = threadIdx.x;
  const int tx = t & 15, ty = t >> 4;
  const int m0 = blockIdx.x * 64;
  const int tn = blockIdx.y;          // 0..47: mat = tn/16, ntile = tn%16
  const int mat = tn >> 4;
  const int n0 = (tn & 15) * 64;
  const float* W    = (mat == 0) ? Wq : (mat == 1) ? Wk : Wv;
  const float* bias = (mat == 0) ? bq : (mat == 1) ? bk : bv;
  float* out = ws + (size_t)mat * (size_t)(NB * SEQ * EMB);

  float acc[4][4] = {};
  const int lk = t & 15, lm = t >> 4;   // A loader: k fast (coalesced 64B)
  const int bn = t & 63, bk0 = t >> 6;  // B loader: n fast (coalesced 256B)

  for (int k0 = 0; k0 < EMB; k0 += 16) {
#pragma unroll
    for (int mm = 0; mm < 4; ++mm)
      As[lk][lm + mm * 16] = hs[(size_t)(m0 + lm + mm * 16) * EMB + k0 + lk];
#pragma unroll
    for (int kk = 0; kk < 4; ++kk)
      Bs[bk0 + kk * 4][bn] = W[(size_t)(k0 + bk0 + kk * 4) * EMB + n0 + bn];
    __syncthreads();
#pragma unroll
    for (int kk = 0; kk < 16; ++kk) {
      const float4 a4 = *(const float4*)&As[kk][ty * 4];
      const float4 b4 = *(const float4*)&Bs[kk][tx * 4];
      const float a[4] = {a4.x, a4.y, a4.z, a4.w};
      const float b[4] = {b4.x, b4.y, b4.z, b4.w};
#pragma unroll
      for (int i = 0; i < 4; ++i)
#pragma unroll
        for (int j = 0; j < 4; ++j) acc[i][j] = fmaf(a[i], b[j], acc[i][j]);
    }
    __syncthreads();
  }
  // write to [bh][s][d] layout
#pragma unroll
  for (int i = 0; i < 4; ++i) {
    const int r  = m0 + ty * 4 + i;        // r = b*SEQ + s
    const int bb = r >> 11, s = r & (SEQ - 1);
#pragma unroll
    for (int j = 0; j < 4; ++j) {
      const int c = n0 + tx * 4 + j;       // c = h*HD + d
      const int h = c >> 6, d = c & 63;
      out[(((size_t)(bb * NH + h)) * SEQ + s) * HD + d] = acc[i][j] + bias[c];
    }
  }
}

__global__ __launch_bounds__(256) void attn_kernel(
    const float* __restrict__ ws, const float* __restrict__ rel_bias,
    float* __restrict__ ctx) {
  __shared__ float QsT[64][68];   // [d][q], pre-scaled by 1/8
  __shared__ float KV[64][68];    // K phase: [d][kc]; V phase: [kc][d]
  __shared__ float Ps[64][68];    // [q][k]
  __shared__ float bias8[32];     // 8 * rel_bias[bucket][h]
  const int t  = threadIdx.x;
  const int tx = t & 15, ty = t >> 4;
  const int qt = blockIdx.x, bh = blockIdx.y;
  const int h = bh & (NH - 1), bb = bh >> 4;
  const float* qp = ws;
  const float* kp = ws + (size_t)NB * SEQ * EMB;
  const float* vp = ws + 2 * (size_t)NB * SEQ * EMB;

  for (int i = t; i < 64 * 64; i += 256) {
    const int qr = i >> 6, d = i & 63;
    QsT[d][qr] = qp[((size_t)bh * SEQ + qt * 64 + qr) * HD + d] * 0.125f;
  }
  if (t < 32) bias8[t] = rel_bias[t * NH + h] * 8.0f;

  float m_run[4], l_run[4], acc[4][4] = {};
#pragma unroll
  for (int i = 0; i < 4; ++i) { m_run[i] = -1e30f; l_run[i] = 0.0f; }

  for (int kt = 0; kt < SEQ / 64; ++kt) {
    // K tile, transposed into LDS
    for (int i = t; i < 64 * 64; i += 256) {
      const int kc = i >> 6, d = i & 63;
      KV[d][kc] = kp[((size_t)bh * SEQ + kt * 64 + kc) * HD + d];
    }
    __syncthreads();

    float sc[4][4] = {};
#pragma unroll 8
    for (int kk = 0; kk < 64; ++kk) {
      const float4 a4 = *(const float4*)&QsT[kk][ty * 4];
      const float4 b4 = *(const float4*)&KV[kk][tx * 4];
      const float a[4] = {a4.x, a4.y, a4.z, a4.w};
      const float b[4] = {b4.x, b4.y, b4.z, b4.w};
#pragma unroll
      for (int i = 0; i < 4; ++i)
#pragma unroll
        for (int j = 0; j < 4; ++j) sc[i][j] = fmaf(a[i], b[j], sc[i][j]);
    }

    // relative-position bias (bidirectional=False: future -> bucket 0)
    const int qg0 = qt * 64 + ty * 4, kg0 = kt * 64 + tx * 4;
#pragma unroll
    for (int i = 0; i < 4; ++i)
#pragma unroll
      for (int j = 0; j < 4; ++j) {
        const int rp = max(qg0 + i - (kg0 + j), 0);
        int bu;
        if (rp < 16) bu = rp;
        else bu = min(16 + (int)(8.0f * __log2f((float)rp * 0.0625f)), 31);
        sc[i][j] += bias8[bu];
      }

    // online softmax (rows = ty*4+i span 16 consecutive lanes, shfl width 16)
#pragma unroll
    for (int i = 0; i < 4; ++i) {
      float mt = fmaxf(fmaxf(sc[i][0], sc[i][1]), fmaxf(sc[i][2], sc[i][3]));
#pragma unroll
      for (int off = 1; off < 16; off <<= 1)
        mt = fmaxf(mt, __shfl_xor(mt, off, 16));
      const float mn  = fmaxf(m_run[i], mt);
      const float fac = __expf(m_run[i] - mn);
      m_run[i] = mn;
      float p[4], rs = 0.0f;
#pragma unroll
      for (int j = 0; j < 4; ++j) { p[j] = __expf(sc[i][j] - mn); rs += p[j]; }
#pragma unroll
      for (int off = 1; off < 16; off <<= 1)
        rs += __shfl_xor(rs, off, 16);
      l_run[i] = l_run[i] * fac + rs;
#pragma unroll
      for (int j = 0; j < 4; ++j) acc[i][j] *= fac;
      *(float4*)&Ps[ty * 4 + i][tx * 4] = make_float4(p[0], p[1], p[2], p[3]);
    }
    __syncthreads();

    // V tile, natural layout
    for (int i = t; i < 64 * 64; i += 256) {
      const int kc = i >> 6, d = i & 63;
      KV[kc][d] = vp[((size_t)bh * SEQ + kt * 64 + kc) * HD + d];
    }
    __syncthreads();

    // PV accumulate, kk unrolled by 4 for float4 LDS reads
#pragma unroll 4
    for (int k4 = 0; k4 < 16; ++k4) {
      float4 a4[4];
#pragma unroll
      for (int i = 0; i < 4; ++i) a4[i] = *(const float4*)&Ps[ty * 4 + i][k4 * 4];
#pragma unroll
      for (int u = 0; u < 4; ++u) {
        const float4 b4 = *(const float4*)&KV[k4 * 4 + u][tx * 4];
        const float bv4[4] = {b4.x, b4.y, b4.z, b4.w};
#pragma unroll
        for (int i = 0; i < 4; ++i) {
          const float au = (u == 0) ? a4[i].x : (u == 1) ? a4[i].y
                         : (u == 2) ? a4[i].z : a4[i].w;
#pragma unroll
          for (int j = 0; j < 4; ++j) acc[i][j] = fmaf(au, bv4[j], acc[i][j]);
        }
      }
    }
    __syncthreads();
  }

  // epilogue: normalize, write ctx [B][S][E]
#pragma unroll
  for (int i = 0; i < 4; ++i) {
    const float inv = 1.0f / l_run[i];
    const int s = qt * 64 + ty * 4 + i;
    float4 o = make_float4(acc[i][0] * inv, acc[i][1] * inv,
                           acc[i][2] * inv, acc[i][3] * inv);
    *(float4*)&ctx[((size_t)bb * SEQ + s) * EMB + h * HD + tx * 4] = o;
  }
}

__global__ __launch_bounds__(256) void out_gemm_kernel(
    const float* __restrict__ ctx, const float* __restrict__ Wo,
    const float* __restrict__ bo, float* __restrict__ out) {
  __shared__ float As[16][68];
  __shared__ float Bs[16][64];
  const int t  = threadIdx.x;
  const int tx = t & 15, ty = t >> 4;
  const int m0 = blockIdx.x * 64;
  const int n0 = blockIdx.y * 64;
  float acc[4][4] = {};
  const int lk = t & 15, lm = t >> 4;
  const int bn = t & 63, bk0 = t >> 6;
  for (int k0 = 0; k0 < EMB; k0 += 16) {
#pragma unroll
    for (int mm = 0; mm < 4; ++mm)
      As[lk][lm + mm * 16] = ctx[(size_t)(m0 + lm + mm * 16) * EMB + k0 + lk];
#pragma unroll
    for (int kk = 0; kk < 4; ++kk)
      Bs[bk0 + kk * 4][bn] = Wo[(size_t)(k0 + bk0 + kk * 4) * EMB + n0 + bn];
    __syncthreads();
#pragma unroll
    for (int kk = 0; kk < 16; ++kk) {
      const float4 a4 = *(const float4*)&As[kk][ty * 4];
      const float4 b4 = *(const float4*)&Bs[kk][tx * 4];
      const float a[4] = {a4.x, a4.y, a4.z, a4.w};
      const float b[4] = {b4.x, b4.y, b4.z, b4.w};
#pragma unroll
      for (int i = 0; i < 4; ++i)
#pragma unroll
        for (int j = 0; j < 4; ++j) acc[i][j] = fmaf(a[i], b[j], acc[i][j]);
    }
    __syncthreads();
  }
#pragma unroll
  for (int i = 0; i < 4; ++i) {
    const int r = m0 + ty * 4 + i;
    const int c0 = n0 + tx * 4;
    float4 o = make_float4(acc[i][0] + bo[c0 + 0], acc[i][1] + bo[c0 + 1],
                           acc[i][2] + bo[c0 + 2], acc[i][3] + bo[c0 + 3]);
    *(float4*)&out[(size_t)r * EMB + c0] = o;
  }
}

extern "C" void kernel_launch(void* const* d_in, const int* in_sizes, int n_in,
                              void* d_out, int out_size, void* d_ws, size_t ws_size,
                              hipStream_t stream) {
  const float* hs = (const float*)d_in[0];
  const float* Wq = (const float*)d_in[1];
  const float* bq = (const float*)d_in[2];
  const float* Wk = (const float*)d_in[3];
  const float* bk = (const float*)d_in[4];
  const float* Wv = (const float*)d_in[5];
  const float* bv = (const float*)d_in[6];
  const float* Wo = (const float*)d_in[7];
  const float* bo = (const float*)d_in[8];
  const float* rb = (const float*)d_in[9];
  float* ws  = (float*)d_ws;
  float* out = (float*)d_out;
  float* ctx = ws + (size_t)3 * NB * SEQ * EMB;

  hipLaunchKernelGGL(qkv_gemm_kernel, dim3(64, 48), dim3(256), 0, stream,
                     hs, Wq, bq, Wk, bk, Wv, bv, ws);
  hipLaunchKernelGGL(attn_kernel, dim3(SEQ / 64, NBH), dim3(256), 0, stream,
                     ws, rb, ctx);
  hipLaunchKernelGGL(out_gemm_kernel, dim3(64, 16), dim3(256), 0, stream,
                     ctx, Wo, bo, out);
}

// Round 3
// 517.765 us; speedup vs baseline: 2.3867x; 2.3867x over previous
//
#include <hip/hip_runtime.h>
#include <math.h>

// Round 3: bf16 hi/lo split (3-pass) MFMA for all matmuls.
// ws layout (ushort units): qh|ql|kh|kl|vh|vl each [32][2048][64] = 4,194,304 elems
// (8 MB each, 48 MB), then ctx f32 [2][2048][1024] = 16 MB. Total 64 MiB.

#define SEQ 2048
#define EMB 1024
#define NH 16
#define HD 64

typedef short v8s __attribute__((ext_vector_type(8)));
typedef float v4f __attribute__((ext_vector_type(4)));
typedef unsigned int v4u __attribute__((ext_vector_type(4)));
typedef unsigned short v4us __attribute__((ext_vector_type(4)));

__device__ __forceinline__ v4f mfma16(v8s a, v8s b, v4f c) {
  return __builtin_amdgcn_mfma_f32_16x16x32_bf16(a, b, c, 0, 0, 0);
}
// f32 -> bf16 RNE (bit trick), and bf16 -> f32
__device__ __forceinline__ unsigned short bfh(float x) {
  unsigned u = __builtin_bit_cast(unsigned, x);
  return (unsigned short)((u + 0x7FFFu + ((u >> 16) & 1u)) >> 16);
}
__device__ __forceinline__ float bff(unsigned short h) {
  unsigned u = (unsigned)h << 16;
  return __builtin_bit_cast(float, u);
}
__device__ __forceinline__ int imin(int a, int b) { return a < b ? a : b; }

// ---------------- shared 128x128 GEMM body (A[M][K] @ B[K][N], K=1024) -------
struct alignas(16) GemmSmem {
  unsigned short Ah[128][40];  // [m][k] hi (stride 80B: 16B-aligned rows)
  unsigned short Al[128][40];
  unsigned short Bh[128][40];  // [n][k] (B^T), k-blocks XOR-swizzled by (n>>4)&3
  unsigned short Bl[128][40];
};

__device__ __forceinline__ void gemm128(const float* __restrict__ A,
                                        const float* __restrict__ B,
                                        int m0, int n0, GemmSmem& S,
                                        v4f acc[4][4]) {
  const int t = threadIdx.x;
  const int l = t & 63, w = t >> 6;
  const int wm = (w >> 1) << 6, wn = (w & 1) << 6;
  const int lg = l >> 4, lc = l & 15;
  const int ar = t >> 1, aks = (t & 1) << 4;   // A stage: row, k-seg
  const int bkr = t >> 3, bns = (t & 7) << 4;  // B stage: k-row, n-seg
  const int bjw = bkr >> 3, bo = bkr & 7;

  for (int k0 = 0; k0 < EMB; k0 += 32) {
    __syncthreads();
    {  // stage A tile (row-wise, no swizzle needed)
      const float* src = A + (size_t)(m0 + ar) * EMB + k0 + aks;
#pragma unroll
      for (int u = 0; u < 4; ++u) {
        const float4 v = *(const float4*)(src + u * 4);
        const unsigned short h0 = bfh(v.x), h1 = bfh(v.y), h2 = bfh(v.z), h3 = bfh(v.w);
        v4us hv = {h0, h1, h2, h3};
        v4us lv = {bfh(v.x - bff(h0)), bfh(v.y - bff(h1)),
                   bfh(v.z - bff(h2)), bfh(v.w - bff(h3))};
        *(v4us*)&S.Ah[ar][aks + u * 4] = hv;
        *(v4us*)&S.Al[ar][aks + u * 4] = lv;
      }
    }
    {  // stage B tile transposed ([n][k]) with k-block swizzle
      const float* src = B + (size_t)(k0 + bkr) * EMB + n0 + bns;
#pragma unroll
      for (int u = 0; u < 4; ++u) {
        const float4 v = *(const float4*)(src + u * 4);
        const float vv[4] = {v.x, v.y, v.z, v.w};
#pragma unroll
        for (int e = 0; e < 4; ++e) {
          const int n = bns + u * 4 + e;
          const int col = ((bjw ^ ((n >> 4) & 3)) << 3) + bo;
          const unsigned short h = bfh(vv[e]);
          S.Bh[n][col] = h;
          S.Bl[n][col] = bfh(vv[e] - bff(h));
        }
      }
    }
    __syncthreads();
    v8s ah[4], al[4], bhf[4], blf[4];
#pragma unroll
    for (int r = 0; r < 4; ++r) {
      ah[r] = *(const v8s*)&S.Ah[wm + r * 16 + lc][lg << 3];
      al[r] = *(const v8s*)&S.Al[wm + r * 16 + lc][lg << 3];
      const int key = ((wn >> 4) + r) & 3;
      bhf[r] = *(const v8s*)&S.Bh[wn + r * 16 + lc][(lg ^ key) << 3];
      blf[r] = *(const v8s*)&S.Bl[wn + r * 16 + lc][(lg ^ key) << 3];
    }
#pragma unroll
    for (int i = 0; i < 4; ++i)
#pragma unroll
      for (int j = 0; j < 4; ++j) {
        acc[i][j] = mfma16(ah[i], bhf[j], acc[i][j]);
        acc[i][j] = mfma16(ah[i], blf[j], acc[i][j]);
        acc[i][j] = mfma16(al[i], bhf[j], acc[i][j]);
      }
  }
}

// ---------------- kernel 1: QKV projection -----------------------------------
__global__ __launch_bounds__(256) void qkv_mfma(
    const float* __restrict__ hs,
    const float* __restrict__ Wq, const float* __restrict__ bq,
    const float* __restrict__ Wk, const float* __restrict__ bk,
    const float* __restrict__ Wv, const float* __restrict__ bv,
    unsigned short* __restrict__ wsu) {
  __shared__ GemmSmem S;
  const int mat = blockIdx.y >> 3;
  const int m0 = blockIdx.x << 7, n0 = (blockIdx.y & 7) << 7;
  const float* B = (mat == 0) ? Wq : (mat == 1) ? Wk : Wv;
  const float* bias = (mat == 0) ? bq : (mat == 1) ? bk : bv;
  unsigned short* oh = wsu + (size_t)mat * 2u * 4194304u;
  unsigned short* ol = oh + 4194304u;
  const float scale = (mat == 0) ? 0.125f : 1.0f;  // fold q * 1/sqrt(64)

  v4f acc[4][4];
#pragma unroll
  for (int i = 0; i < 4; ++i)
#pragma unroll
    for (int j = 0; j < 4; ++j) acc[i][j] = 0.0f;

  gemm128(hs, B, m0, n0, S, acc);

  const int t = threadIdx.x, l = t & 63, w = t >> 6;
  const int wm = (w >> 1) << 6, wn = (w & 1) << 6, lg = l >> 4, lc = l & 15;
#pragma unroll
  for (int i = 0; i < 4; ++i)
#pragma unroll
    for (int j = 0; j < 4; ++j)
#pragma unroll
      for (int jr = 0; jr < 4; ++jr) {
        const int r = m0 + wm + i * 16 + lg * 4 + jr;   // b*2048 + s
        const int cm = n0 + wn + j * 16 + lc;           // h*64 + d
        const float val = (acc[i][j][jr] + bias[cm]) * scale;
        const unsigned short h = bfh(val);
        const unsigned short lo = bfh(val - bff(h));
        const size_t idx =
            (((size_t)((r >> 11) * NH + (cm >> 6)) * SEQ) + (r & 2047)) * HD + (cm & 63);
        oh[idx] = h;
        ol[idx] = lo;
      }
}

// ---------------- kernel 2: flash attention ----------------------------------
struct alignas(16) AttnSmem {
  unsigned short Kh[32][72], Kl[32][72];  // [kv][d]
  unsigned short VTh[64][40], VTl[64][40];  // [d][kv]
  unsigned int Pq[256][44];               // p_hi | p_lo<<16, [q][kv]
  float bias8[32];
};

__global__ __launch_bounds__(512) void attn_mfma(
    const unsigned short* __restrict__ wsu,
    const float* __restrict__ rel_bias, float* __restrict__ ctx) {
  __shared__ AttnSmem S;
  const unsigned short* qh = wsu;
  const unsigned short* ql = wsu + 4194304u;
  const unsigned short* kh = wsu + 2u * 4194304u;
  const unsigned short* kl = wsu + 3u * 4194304u;
  const unsigned short* vh = wsu + 4u * 4194304u;
  const unsigned short* vl = wsu + 5u * 4194304u;

  const int t = threadIdx.x;
  const int w = t >> 6, l = t & 63, lg = l >> 4, lc = l & 15;
  const int qt = blockIdx.x, bh = blockIdx.y, hh = bh & 15;
  const int q0 = qt << 8;

  if (t < 32) S.bias8[t] = rel_bias[t * NH + hh] * 8.0f;

  // Q fragments in registers (already scaled by 1/8)
  v8s qfh[2][2], qfl[2][2];
#pragma unroll
  for (int mr = 0; mr < 2; ++mr)
#pragma unroll
    for (int dc = 0; dc < 2; ++dc) {
      const size_t off =
          (((size_t)bh * SEQ) + q0 + w * 32 + mr * 16 + lc) * HD + dc * 32 + lg * 8;
      qfh[mr][dc] = *(const v8s*)(qh + off);
      qfl[mr][dc] = *(const v8s*)(ql + off);
    }

  float m_run[2][4], l_run[2][4];
  v4f acc[2][4];
#pragma unroll
  for (int mr = 0; mr < 2; ++mr) {
#pragma unroll
    for (int j = 0; j < 4; ++j) { m_run[mr][j] = -1e30f; l_run[mr][j] = 0.0f; }
#pragma unroll
    for (int dn = 0; dn < 4; ++dn) acc[mr][dn] = 0.0f;
  }

  const int tt = t & 255, skv = tt >> 3, sd8 = (tt & 7) << 3;

  for (int kt = 0; kt < SEQ / 32; ++kt) {
    const int kv0 = kt << 5;
    __syncthreads();  // prior-tile LDS reads complete
    {
      const size_t g = (((size_t)bh * SEQ) + kv0 + skv) * HD + sd8;
      if (t < 256) {
        *(v8s*)&S.Kh[skv][sd8] = *(const v8s*)(kh + g);
        const v8s vv = *(const v8s*)(vh + g);
#pragma unroll
        for (int e = 0; e < 8; ++e) S.VTh[sd8 + e][skv] = (unsigned short)vv[e];
      } else {
        *(v8s*)&S.Kl[skv][sd8] = *(const v8s*)(kl + g);
        const v8s vv = *(const v8s*)(vl + g);
#pragma unroll
        for (int e = 0; e < 8; ++e) S.VTl[sd8 + e][skv] = (unsigned short)vv[e];
      }
    }
    __syncthreads();

    // ---- QK^T (3-pass split) ----
    v4f sc[2][2];
    sc[0][0] = 0.0f; sc[0][1] = 0.0f; sc[1][0] = 0.0f; sc[1][1] = 0.0f;
    {
      v8s kbh[2][2], kbl[2][2];
#pragma unroll
      for (int fn = 0; fn < 2; ++fn)
#pragma unroll
        for (int dc = 0; dc < 2; ++dc) {
          kbh[fn][dc] = *(const v8s*)&S.Kh[fn * 16 + lc][dc * 32 + lg * 8];
          kbl[fn][dc] = *(const v8s*)&S.Kl[fn * 16 + lc][dc * 32 + lg * 8];
        }
#pragma unroll
      for (int mr = 0; mr < 2; ++mr)
#pragma unroll
        for (int fn = 0; fn < 2; ++fn)
#pragma unroll
          for (int dc = 0; dc < 2; ++dc) {
            sc[mr][fn] = mfma16(qfh[mr][dc], kbh[fn][dc], sc[mr][fn]);
            sc[mr][fn] = mfma16(qfh[mr][dc], kbl[fn][dc], sc[mr][fn]);
            sc[mr][fn] = mfma16(qfl[mr][dc], kbh[fn][dc], sc[mr][fn]);
          }
    }

    // ---- rel-pos bias: uniform fast paths for 92% of tiles ----
    const int dlt = q0 + w * 32 - kv0;  // q - k at tile origin (wave-uniform)
    if (dlt < 0) {  // whole tile is "future": rp=0 -> bucket 0
      const float bb = S.bias8[0];
#pragma unroll
      for (int mr = 0; mr < 2; ++mr)
#pragma unroll
        for (int fn = 0; fn < 2; ++fn) sc[mr][fn] += bb;
    } else if (dlt >= 90) {  // min rp >= 59 -> bucket 31 everywhere
      const float bb = S.bias8[31];
#pragma unroll
      for (int mr = 0; mr < 2; ++mr)
#pragma unroll
        for (int fn = 0; fn < 2; ++fn) sc[mr][fn] += bb;
    } else {
#pragma unroll
      for (int mr = 0; mr < 2; ++mr)
#pragma unroll
        for (int fn = 0; fn < 2; ++fn)
#pragma unroll
          for (int j = 0; j < 4; ++j) {
            const int rp0 = dlt + mr * 16 + lg * 4 + j - (fn * 16 + lc);
            const int rp = rp0 > 0 ? rp0 : 0;
            const int bu = (rp < 16)
                ? rp
                : imin(16 + (int)(8.0f * __log2f((float)rp * 0.0625f)), 31);
            sc[mr][fn][j] += S.bias8[bu];
          }
    }

    // ---- online softmax (rows live across 16-lane groups) ----
#pragma unroll
    for (int mr = 0; mr < 2; ++mr) {
#pragma unroll
      for (int j = 0; j < 4; ++j) {
        float mt = fmaxf(sc[mr][0][j], sc[mr][1][j]);
        mt = fmaxf(mt, __shfl_xor(mt, 1));
        mt = fmaxf(mt, __shfl_xor(mt, 2));
        mt = fmaxf(mt, __shfl_xor(mt, 4));
        mt = fmaxf(mt, __shfl_xor(mt, 8));
        const float mo = m_run[mr][j];
        const float mn = fmaxf(mo, mt);
        const float fac = __expf(mo - mn);
        m_run[mr][j] = mn;
        const float p0 = __expf(sc[mr][0][j] - mn);
        const float p1 = __expf(sc[mr][1][j] - mn);
        float rs = p0 + p1;
        rs += __shfl_xor(rs, 1);
        rs += __shfl_xor(rs, 2);
        rs += __shfl_xor(rs, 4);
        rs += __shfl_xor(rs, 8);
        l_run[mr][j] = l_run[mr][j] * fac + rs;
#pragma unroll
        for (int dn = 0; dn < 4; ++dn) acc[mr][dn][j] *= fac;
        // P -> bf16 hi/lo packed u32
        const unsigned short h0 = bfh(p0);
        const unsigned short g0 = bfh(p0 - bff(h0));
        const unsigned short h1 = bfh(p1);
        const unsigned short g1 = bfh(p1 - bff(h1));
        const int prow = w * 32 + mr * 16 + lg * 4 + j;
        S.Pq[prow][lc] = (unsigned)h0 | ((unsigned)g0 << 16);
        S.Pq[prow][16 + lc] = (unsigned)h1 | ((unsigned)g1 << 16);
      }
    }

    // ---- PV (3-pass split), same-wave P reuse (no barrier needed) ----
    {
      v8s vbh[4], vbl[4];
#pragma unroll
      for (int dn = 0; dn < 4; ++dn) {
        vbh[dn] = *(const v8s*)&S.VTh[dn * 16 + lc][lg * 8];
        vbl[dn] = *(const v8s*)&S.VTl[dn * 16 + lc][lg * 8];
      }
#pragma unroll
      for (int mr = 0; mr < 2; ++mr) {
        const unsigned* pr = &S.Pq[w * 32 + mr * 16 + lc][lg * 8];
        const v4u pa = *(const v4u*)pr;
        const v4u pb = *(const v4u*)(pr + 4);
        v8s ph, pl;
#pragma unroll
        for (int e = 0; e < 4; ++e) {
          ph[e] = (short)(pa[e] & 0xFFFFu);
          pl[e] = (short)(pa[e] >> 16);
          ph[4 + e] = (short)(pb[e] & 0xFFFFu);
          pl[4 + e] = (short)(pb[e] >> 16);
        }
#pragma unroll
        for (int dn = 0; dn < 4; ++dn) {
          acc[mr][dn] = mfma16(ph, vbh[dn], acc[mr][dn]);
          acc[mr][dn] = mfma16(ph, vbl[dn], acc[mr][dn]);
          acc[mr][dn] = mfma16(pl, vbh[dn], acc[mr][dn]);
        }
      }
    }
  }

  // epilogue: normalize + write ctx [B][S][E]
  const int b = bh >> 4;
#pragma unroll
  for (int mr = 0; mr < 2; ++mr)
#pragma unroll
    for (int j = 0; j < 4; ++j) {
      const float inv = 1.0f / l_run[mr][j];
      const int srow = q0 + w * 32 + mr * 16 + lg * 4 + j;
      float* dst = ctx + ((size_t)b * SEQ + srow) * EMB + hh * HD;
#pragma unroll
      for (int dn = 0; dn < 4; ++dn) dst[dn * 16 + lc] = acc[mr][dn][j] * inv;
    }
}

// ---------------- kernel 3: output projection --------------------------------
__global__ __launch_bounds__(256) void out_mfma(
    const float* __restrict__ ctx, const float* __restrict__ Wo,
    const float* __restrict__ bo, float* __restrict__ out) {
  __shared__ GemmSmem S;
  const int m0 = blockIdx.x << 7, n0 = blockIdx.y << 7;
  v4f acc[4][4];
#pragma unroll
  for (int i = 0; i < 4; ++i)
#pragma unroll
    for (int j = 0; j < 4; ++j) acc[i][j] = 0.0f;

  gemm128(ctx, Wo, m0, n0, S, acc);

  const int t = threadIdx.x, l = t & 63, w = t >> 6;
  const int wm = (w >> 1) << 6, wn = (w & 1) << 6, lg = l >> 4, lc = l & 15;
#pragma unroll
  for (int i = 0; i < 4; ++i)
#pragma unroll
    for (int j = 0; j < 4; ++j)
#pragma unroll
      for (int jr = 0; jr < 4; ++jr) {
        const int r = m0 + wm + i * 16 + lg * 4 + jr;
        const int c = n0 + wn + j * 16 + lc;
        out[(size_t)r * EMB + c] = acc[i][j][jr] + bo[c];
      }
}

extern "C" void kernel_launch(void* const* d_in, const int* in_sizes, int n_in,
                              void* d_out, int out_size, void* d_ws, size_t ws_size,
                              hipStream_t stream) {
  const float* hs = (const float*)d_in[0];
  const float* Wq = (const float*)d_in[1];
  const float* bq = (const float*)d_in[2];
  const float* Wk = (const float*)d_in[3];
  const float* bk = (const float*)d_in[4];
  const float* Wv = (const float*)d_in[5];
  const float* bv = (const float*)d_in[6];
  const float* Wo = (const float*)d_in[7];
  const float* bo = (const float*)d_in[8];
  const float* rb = (const float*)d_in[9];
  unsigned short* wsu = (unsigned short*)d_ws;
  float* ctx = (float*)((char*)d_ws + 6ull * 8388608ull);  // after 6 bf16 arrays

  hipLaunchKernelGGL(qkv_mfma, dim3(32, 24), dim3(256), 0, stream,
                     hs, Wq, bq, Wk, bk, Wv, bv, wsu);
  hipLaunchKernelGGL(attn_mfma, dim3(8, 32), dim3(512), 0, stream, wsu, rb, ctx);
  hipLaunchKernelGGL(out_mfma, dim3(32, 8), dim3(256), 0, stream,
                     ctx, Wo, bo, (float*)d_out);
}

// Round 4
// 379.808 us; speedup vs baseline: 3.2535x; 1.3632x over previous
//
#include <hip/hip_runtime.h>
#include <math.h>

// Round 4: prepass-split bf16 GEMMs + swapped-operand 32x32 MFMA flash attention.
// ws layout (units of MU = 1M ushorts = 2MB):
//  qh:0 ql:4 kh:8 kl:12 vh:16 vl:20 vth:24 vtl:28 ah/ctxh:32 al/ctxl:36
//  WqTh:40 WqTl:41 WkTh:42 WkTl:43 WvTh:44 WvTl:45 WoTh:46 WoTl:47  (total 96MB)

#define SEQ 2048
#define EMB 1024
#define NH 16
#define HD 64
#define LOG2E 1.44269504088896340736f
#define MU (1u << 20)

typedef short v8s __attribute__((ext_vector_type(8)));
typedef float v4f __attribute__((ext_vector_type(4)));
typedef float v16f __attribute__((ext_vector_type(16)));
typedef unsigned int v4u __attribute__((ext_vector_type(4)));

__device__ __forceinline__ v4f mfma16(v8s a, v8s b, v4f c) {
  return __builtin_amdgcn_mfma_f32_16x16x32_bf16(a, b, c, 0, 0, 0);
}
__device__ __forceinline__ v16f mfma32(v8s a, v8s b, v16f c) {
  return __builtin_amdgcn_mfma_f32_32x32x16_bf16(a, b, c, 0, 0, 0);
}
__device__ __forceinline__ unsigned short bfh(float x) {
  unsigned u = __builtin_bit_cast(unsigned, x);
  return (unsigned short)((u + 0x7FFFu + ((u >> 16) & 1u)) >> 16);
}
__device__ __forceinline__ float bff(unsigned short h) {
  unsigned u = (unsigned)h << 16;
  return __builtin_bit_cast(float, u);
}
__device__ __forceinline__ int imin(int a, int b) { return a < b ? a : b; }

// pack (a,b) -> bf16 pair hi-word u32 + residual bf16 pair u32 (lo = src0 in bits 15:0)
__device__ __forceinline__ void split2(float a, float b, unsigned& uh, unsigned& ul) {
  unsigned h;
  asm("v_cvt_pk_bf16_f32 %0, %1, %2" : "=v"(h) : "v"(a), "v"(b));
  const float ra = __builtin_bit_cast(float, h << 16);
  const float rb = __builtin_bit_cast(float, h & 0xFFFF0000u);
  unsigned lo;
  const float la = a - ra, lb = b - rb;
  asm("v_cvt_pk_bf16_f32 %0, %1, %2" : "=v"(lo) : "v"(la), "v"(lb));
  uh = h;
  ul = lo;
}

// ---------------- prepass: hs split + W transpose/split -----------------------
__global__ __launch_bounds__(256) void prep_kernel(
    const float* __restrict__ hs, const float* __restrict__ Wq,
    const float* __restrict__ Wk, const float* __restrict__ Wv,
    const float* __restrict__ Wo, unsigned short* __restrict__ wsu) {
  __shared__ float T[64][68];
  const int t = threadIdx.x;
  const int z = blockIdx.z;
  if (z == 4) {
    unsigned short* ah = wsu + 32u * MU;
    unsigned short* al = wsu + 36u * MU;
    const int base = (blockIdx.y * 16 + blockIdx.x) * 16384 + t * 4;
#pragma unroll
    for (int i = 0; i < 16; ++i) {
      const int idx = base + i * 1024;
      const float4 v = *(const float4*)(hs + idx);
      unsigned h0, l0, h1, l1;
      split2(v.x, v.y, h0, l0);
      split2(v.z, v.w, h1, l1);
      *(uint2*)&ah[idx] = make_uint2(h0, h1);
      *(uint2*)&al[idx] = make_uint2(l0, l1);
    }
    return;
  }
  const float* W = (z == 0) ? Wq : (z == 1) ? Wk : (z == 2) ? Wv : Wo;
  const float s = (z == 0) ? 0.125f * LOG2E : 1.0f;
  unsigned short* WTh = wsu + (size_t)(40u + 2u * z) * MU;
  unsigned short* WTl = WTh + MU;
  const int n0 = blockIdx.x * 64, k0 = blockIdx.y * 64;
  const int r = t >> 2, cs = (t & 3) * 16;
#pragma unroll
  for (int i = 0; i < 4; ++i)
    *(float4*)&T[r][cs + i * 4] =
        *(const float4*)(W + (size_t)(k0 + r) * EMB + n0 + cs + i * 4);
  __syncthreads();
  unsigned short hb[16], lb[16];
#pragma unroll
  for (int i = 0; i < 16; i += 2) {
    const float a = T[cs + i][r] * s, b2 = T[cs + i + 1][r] * s;
    unsigned uh, ul;
    split2(a, b2, uh, ul);
    hb[i] = (unsigned short)(uh & 0xFFFFu);
    hb[i + 1] = (unsigned short)(uh >> 16);
    lb[i] = (unsigned short)(ul & 0xFFFFu);
    lb[i + 1] = (unsigned short)(ul >> 16);
  }
  const size_t go = (size_t)(n0 + r) * EMB + k0 + cs;
  *(v8s*)&WTh[go] = *(v8s*)&hb[0];
  *(v8s*)&WTh[go + 8] = *(v8s*)&hb[8];
  *(v8s*)&WTl[go] = *(v8s*)&lb[0];
  *(v8s*)&WTl[go + 8] = *(v8s*)&lb[8];
}

// ---------------- 128x128 bf16 GEMM body (A[m][k] hi/lo, BT[n][k] hi/lo) -----
struct alignas(16) GemmSmem {
  unsigned short Ah[128][40], Al[128][40], Bh[128][40], Bl[128][40];
};

__device__ __forceinline__ void gemm128_bf(
    const unsigned short* __restrict__ Ah_g, const unsigned short* __restrict__ Al_g,
    const unsigned short* __restrict__ Bh_g, const unsigned short* __restrict__ Bl_g,
    int m0, int n0, GemmSmem& S, v4f acc[4][4]) {
  const int t = threadIdx.x;
  const int l = t & 63, w = t >> 6;
  const int wm = (w >> 1) << 6, wn = (w & 1) << 6;
  const int lg = l >> 4, lc = l & 15;
  const int sr = t >> 2, skc = (t & 3) * 8;
  for (int k0 = 0; k0 < EMB; k0 += 32) {
    __syncthreads();
    {
      const size_t a0 = (size_t)(m0 + sr) * EMB + k0 + skc;
      const size_t a1 = (size_t)(m0 + 64 + sr) * EMB + k0 + skc;
      *(v8s*)&S.Ah[sr][skc] = *(const v8s*)(Ah_g + a0);
      *(v8s*)&S.Ah[64 + sr][skc] = *(const v8s*)(Ah_g + a1);
      *(v8s*)&S.Al[sr][skc] = *(const v8s*)(Al_g + a0);
      *(v8s*)&S.Al[64 + sr][skc] = *(const v8s*)(Al_g + a1);
      const size_t b0 = (size_t)(n0 + sr) * EMB + k0 + skc;
      const size_t b1 = (size_t)(n0 + 64 + sr) * EMB + k0 + skc;
      *(v8s*)&S.Bh[sr][skc] = *(const v8s*)(Bh_g + b0);
      *(v8s*)&S.Bh[64 + sr][skc] = *(const v8s*)(Bh_g + b1);
      *(v8s*)&S.Bl[sr][skc] = *(const v8s*)(Bl_g + b0);
      *(v8s*)&S.Bl[64 + sr][skc] = *(const v8s*)(Bl_g + b1);
    }
    __syncthreads();
    v8s ah[4], al[4], bh[4], bl[4];
#pragma unroll
    for (int r = 0; r < 4; ++r) {
      ah[r] = *(const v8s*)&S.Ah[wm + r * 16 + lc][lg * 8];
      al[r] = *(const v8s*)&S.Al[wm + r * 16 + lc][lg * 8];
      bh[r] = *(const v8s*)&S.Bh[wn + r * 16 + lc][lg * 8];
      bl[r] = *(const v8s*)&S.Bl[wn + r * 16 + lc][lg * 8];
    }
#pragma unroll
    for (int i = 0; i < 4; ++i)
#pragma unroll
      for (int j = 0; j < 4; ++j) {
        acc[i][j] = mfma16(ah[i], bh[j], acc[i][j]);
        acc[i][j] = mfma16(ah[i], bl[j], acc[i][j]);
        acc[i][j] = mfma16(al[i], bh[j], acc[i][j]);
      }
  }
}

// ---------------- kernel: QKV projection -------------------------------------
__global__ __launch_bounds__(256) void qkv_mfma(
    const float* __restrict__ bq, const float* __restrict__ bk,
    const float* __restrict__ bv, unsigned short* __restrict__ wsu) {
  __shared__ GemmSmem S;
  const int mat = blockIdx.y >> 3;
  const int m0 = blockIdx.x << 7, n0 = (blockIdx.y & 7) << 7;
  const unsigned short* Ah_g = wsu + 32u * MU;
  const unsigned short* Al_g = wsu + 36u * MU;
  const unsigned short* Bh_g = wsu + (size_t)(40u + 2u * mat) * MU;
  const unsigned short* Bl_g = Bh_g + MU;
  const float* bias = (mat == 0) ? bq : (mat == 1) ? bk : bv;
  const float bs = (mat == 0) ? 0.125f * LOG2E : 1.0f;
  unsigned short* oh = wsu + (size_t)mat * 8u * MU;
  unsigned short* ol = oh + 4u * MU;

  v4f acc[4][4] = {};
  gemm128_bf(Ah_g, Al_g, Bh_g, Bl_g, m0, n0, S, acc);

  const int t = threadIdx.x, l = t & 63, w = t >> 6;
  const int wm = (w >> 1) << 6, wn = (w & 1) << 6, lg = l >> 4, lc = l & 15;
#pragma unroll
  for (int i = 0; i < 4; ++i)
#pragma unroll
    for (int j = 0; j < 4; ++j)
#pragma unroll
      for (int jr = 0; jr < 4; ++jr) {
        const int r = m0 + wm + i * 16 + lg * 4 + jr;  // b*2048 + s
        const int cm = n0 + wn + j * 16 + lc;          // h*64 + d
        const float val = acc[i][j][jr] + bias[cm] * bs;
        const unsigned short h = bfh(val);
        const unsigned short lo = bfh(val - bff(h));
        const size_t idx =
            (((size_t)((r >> 11) * NH + (cm >> 6)) * SEQ) + (r & 2047)) * HD + (cm & 63);
        oh[idx] = h;
        ol[idx] = lo;
      }
}

// ---------------- kernel: V transpose ----------------------------------------
__global__ __launch_bounds__(256) void vtrans_kernel(unsigned short* __restrict__ wsu) {
  __shared__ unsigned short Th[64][72], Tl[64][72];
  const int t = threadIdx.x;
  const int s0 = blockIdx.x * 64, bh = blockIdx.y;
  const unsigned short* vh = wsu + 16u * MU;
  const unsigned short* vl = wsu + 20u * MU;
  unsigned short* vth = wsu + 24u * MU;
  unsigned short* vtl = wsu + 28u * MU;
  const int r = t >> 2, cs = (t & 3) * 16;
  const size_t g = ((size_t)bh * SEQ + s0 + r) * HD + cs;
  *(v8s*)&Th[r][cs] = *(const v8s*)(vh + g);
  *(v8s*)&Th[r][cs + 8] = *(const v8s*)(vh + g + 8);
  *(v8s*)&Tl[r][cs] = *(const v8s*)(vl + g);
  *(v8s*)&Tl[r][cs + 8] = *(const v8s*)(vl + g + 8);
  __syncthreads();
  unsigned short hb[16], lb[16];
#pragma unroll
  for (int i = 0; i < 16; ++i) {
    hb[i] = Th[cs + i][r];
    lb[i] = Tl[cs + i][r];
  }
  const size_t go = ((size_t)bh * HD + r) * SEQ + s0 + cs;
  *(v8s*)&vth[go] = *(v8s*)&hb[0];
  *(v8s*)&vth[go + 8] = *(v8s*)&hb[8];
  *(v8s*)&vtl[go] = *(v8s*)&lb[0];
  *(v8s*)&vtl[go + 8] = *(v8s*)&lb[8];
}

// ---------------- kernel: flash attention (32x32, swapped operands) ----------
struct alignas(16) AttnSmem {
  unsigned short Kh[32][72], Kl[32][72];
  unsigned short VTh[64][40], VTl[64][40];
  float bias8[32];
};

// rebuild PV B-fragment (k = (l>>5)*8+e) from S^T C-layout pairs via half swap
__device__ __forceinline__ v8s pfrag(unsigned a0, unsigned a1, unsigned a2,
                                     unsigned a3, int h5) {
  const unsigned sa = (unsigned)__shfl_xor((int)(h5 ? a0 : a2), 32, 64);
  const unsigned sb = (unsigned)__shfl_xor((int)(h5 ? a1 : a3), 32, 64);
  v4u r;
  r[0] = h5 ? sa : a0;
  r[1] = h5 ? sb : a1;
  r[2] = h5 ? a2 : sa;
  r[3] = h5 ? a3 : sb;
  return __builtin_bit_cast(v8s, r);
}

__global__ __launch_bounds__(256) void attn_mfma(
    const float* __restrict__ rel_bias, unsigned short* __restrict__ wsu) {
  __shared__ AttnSmem S;
  const int t = threadIdx.x;
  const int bid = blockIdx.x;
  const int nid = (bid & 7) * 64 + (bid >> 3);  // XCD swizzle (512 = 8*64)
  const int qt = nid & 15, bh = nid >> 4;
  const int hh = bh & 15, b = bh >> 4;
  const int w = t >> 6, l = t & 63;
  const int lq = l & 31, h5 = l >> 5;
  const int qbase = qt * 128 + w * 32;

  const unsigned short* qh = wsu;
  const unsigned short* ql = wsu + 4u * MU;
  const unsigned short* kh = wsu + 8u * MU;
  const unsigned short* kl = wsu + 12u * MU;
  const unsigned short* vth = wsu + 24u * MU;
  const unsigned short* vtl = wsu + 28u * MU;
  unsigned short* ctxh = wsu + 32u * MU;
  unsigned short* ctxl = wsu + 36u * MU;

  if (t < 32) S.bias8[t] = rel_bias[t * NH + hh] * 8.0f * LOG2E;

  v8s qfh[4], qfl[4];
  const size_t qg = ((size_t)bh * SEQ + qbase + lq) * HD;
#pragma unroll
  for (int dc = 0; dc < 4; ++dc) {
    qfh[dc] = *(const v8s*)(qh + qg + dc * 16 + h5 * 8);
    qfl[dc] = *(const v8s*)(ql + qg + dc * 16 + h5 * 8);
  }

  float m_run = -1e30f, l_run = 0.0f;
  v16f acc[2] = {};

  const int krs = t >> 3, kcs = (t & 7) * 8;  // K stage: 32x64
  const int vrs = t >> 2, vcs = (t & 3) * 8;  // VT stage: 64x32

  for (int kt = 0; kt < SEQ / 32; ++kt) {
    const int kv0 = kt * 32;
    __syncthreads();
    {
      const size_t g = ((size_t)bh * SEQ + kv0 + krs) * HD + kcs;
      *(v8s*)&S.Kh[krs][kcs] = *(const v8s*)(kh + g);
      *(v8s*)&S.Kl[krs][kcs] = *(const v8s*)(kl + g);
      const size_t gv = ((size_t)bh * HD + vrs) * SEQ + kv0 + vcs;
      *(v8s*)&S.VTh[vrs][vcs] = *(const v8s*)(vth + gv);
      *(v8s*)&S.VTl[vrs][vcs] = *(const v8s*)(vtl + gv);
    }
    __syncthreads();

    // QK^T swapped: sc = K*Q -> S^T fragment (rows k, cols q=lq), 3-pass split
    v16f sc = {};
#pragma unroll
    for (int dc = 0; dc < 4; ++dc) {
      const v8s kfh = *(const v8s*)&S.Kh[lq][dc * 16 + h5 * 8];
      const v8s kfl = *(const v8s*)&S.Kl[lq][dc * 16 + h5 * 8];
      sc = mfma32(kfh, qfh[dc], sc);
      sc = mfma32(kfh, qfl[dc], sc);
      sc = mfma32(kfl, qfh[dc], sc);
    }

    // rel-pos bias (log2 domain)
    const int dq = qbase - kv0;
    if (dq + 31 <= 0) {
      const float bb = S.bias8[0];
#pragma unroll
      for (int r = 0; r < 16; ++r) sc[r] += bb;
    } else if (dq - 31 >= 59) {
      const float bb = S.bias8[31];
#pragma unroll
      for (int r = 0; r < 16; ++r) sc[r] += bb;
    } else {
#pragma unroll
      for (int r = 0; r < 16; ++r) {
        const int krow = (r & 3) + 8 * (r >> 2) + 4 * h5;
        int rp = (qbase + lq) - (kv0 + krow);
        rp = rp > 0 ? rp : 0;
        const int bu =
            rp < 16 ? rp : imin(16 + (int)(8.0f * __log2f((float)rp * 0.0625f)), 31);
        sc[r] += S.bias8[bu];
      }
    }

    // online softmax: q is lane-local (col = lq); reduce over regs + half swap
    float mt = sc[0];
#pragma unroll
    for (int r = 1; r < 16; ++r) mt = fmaxf(mt, sc[r]);
    mt = fmaxf(mt, __shfl_xor(mt, 32, 64));
    const float mn = fmaxf(m_run, mt);
    const float fac = exp2f(m_run - mn);
    m_run = mn;
    float p[16];
    float rs = 0.0f;
#pragma unroll
    for (int r = 0; r < 16; ++r) {
      p[r] = exp2f(sc[r] - mn);
      rs += p[r];
    }
    rs += __shfl_xor(rs, 32, 64);
    l_run = l_run * fac + rs;
#pragma unroll
    for (int r = 0; r < 16; ++r) {
      acc[0][r] *= fac;
      acc[1][r] *= fac;
    }

    // P -> bf16 hi/lo pairs in registers
    unsigned pkh[8], pkl[8];
#pragma unroll
    for (int i = 0; i < 8; ++i) split2(p[2 * i], p[2 * i + 1], pkh[i], pkl[i]);

    // PV: acc[db] (O^T: rows d, cols q) += VT * P, 3-pass split
#pragma unroll
    for (int ks = 0; ks < 2; ++ks) {
      const v8s pbh = pfrag(pkh[ks * 4], pkh[ks * 4 + 1], pkh[ks * 4 + 2],
                            pkh[ks * 4 + 3], h5);
      const v8s pbl = pfrag(pkl[ks * 4], pkl[ks * 4 + 1], pkl[ks * 4 + 2],
                            pkl[ks * 4 + 3], h5);
#pragma unroll
      for (int db = 0; db < 2; ++db) {
        const v8s vfh = *(const v8s*)&S.VTh[db * 32 + lq][ks * 16 + h5 * 8];
        const v8s vfl = *(const v8s*)&S.VTl[db * 32 + lq][ks * 16 + h5 * 8];
        acc[db] = mfma32(vfh, pbh, acc[db]);
        acc[db] = mfma32(vfh, pbl, acc[db]);
        acc[db] = mfma32(vfl, pbh, acc[db]);
      }
    }
  }

  // epilogue: normalize, split to ctx hi/lo bf16 (feeds out-proj GEMM)
  const float inv = 1.0f / l_run;
  const size_t rowb = ((size_t)b * SEQ + qbase + lq) * EMB + hh * HD;
#pragma unroll
  for (int db = 0; db < 2; ++db)
#pragma unroll
    for (int i = 0; i < 8; ++i) {
      const float a = acc[db][2 * i] * inv, c = acc[db][2 * i + 1] * inv;
      unsigned uh, ul;
      split2(a, c, uh, ul);
      const int d0 = db * 32 + 8 * (i >> 1) + 4 * h5 + 2 * (i & 1);
      *(unsigned*)&ctxh[rowb + d0] = uh;
      *(unsigned*)&ctxl[rowb + d0] = ul;
    }
}

// ---------------- kernel: output projection ----------------------------------
__global__ __launch_bounds__(256) void out_mfma(
    const float* __restrict__ bo, float* __restrict__ out,
    unsigned short* __restrict__ wsu) {
  __shared__ GemmSmem S;
  const int m0 = blockIdx.x << 7, n0 = blockIdx.y << 7;
  const unsigned short* Ah_g = wsu + 32u * MU;
  const unsigned short* Al_g = wsu + 36u * MU;
  const unsigned short* Bh_g = wsu + 46u * MU;
  const unsigned short* Bl_g = wsu + 47u * MU;
  v4f acc[4][4] = {};
  gemm128_bf(Ah_g, Al_g, Bh_g, Bl_g, m0, n0, S, acc);
  const int t = threadIdx.x, l = t & 63, w = t >> 6;
  const int wm = (w >> 1) << 6, wn = (w & 1) << 6, lg = l >> 4, lc = l & 15;
#pragma unroll
  for (int i = 0; i < 4; ++i)
#pragma unroll
    for (int j = 0; j < 4; ++j)
#pragma unroll
      for (int jr = 0; jr < 4; ++jr) {
        const int r = m0 + wm + i * 16 + lg * 4 + jr;
        const int c = n0 + wn + j * 16 + lc;
        out[(size_t)r * EMB + c] = acc[i][j][jr] + bo[c];
      }
}

extern "C" void kernel_launch(void* const* d_in, const int* in_sizes, int n_in,
                              void* d_out, int out_size, void* d_ws, size_t ws_size,
                              hipStream_t stream) {
  const float* hs = (const float*)d_in[0];
  const float* Wq = (const float*)d_in[1];
  const float* bq = (const float*)d_in[2];
  const float* Wk = (const float*)d_in[3];
  const float* bk = (const float*)d_in[4];
  const float* Wv = (const float*)d_in[5];
  const float* bv = (const float*)d_in[6];
  const float* Wo = (const float*)d_in[7];
  const float* bo = (const float*)d_in[8];
  const float* rb = (const float*)d_in[9];
  unsigned short* wsu = (unsigned short*)d_ws;

  hipLaunchKernelGGL(prep_kernel, dim3(16, 16, 5), dim3(256), 0, stream,
                     hs, Wq, Wk, Wv, Wo, wsu);
  hipLaunchKernelGGL(qkv_mfma, dim3(32, 24), dim3(256), 0, stream, bq, bk, bv, wsu);
  hipLaunchKernelGGL(vtrans_kernel, dim3(32, 32), dim3(256), 0, stream, wsu);
  hipLaunchKernelGGL(attn_mfma, dim3(512), dim3(256), 0, stream, rb, wsu);
  hipLaunchKernelGGL(out_mfma, dim3(32, 8), dim3(256), 0, stream, bo, (float*)d_out, wsu);
}

// Round 5
// 375.717 us; speedup vs baseline: 3.2890x; 1.0109x over previous
//
#include <hip/hip_runtime.h>
#include <math.h>

// Round 5: attn latency attack — KVBLK=64, dbuf LDS (1 barrier/iter), async reg
// staging, granule-XOR swizzle, P-hi-only PV, defer-max, setprio. vtrans fused
// into qkv epilogue.
// ws layout (MU = 1M ushorts = 2MB):
//  qh:0 ql:4 kh:8 kl:12 vth:16 vtl:20 ctxh:24 ctxl:28 hsh:32 hsl:36
//  WqTh:40 WqTl:41 WkTh:42 WkTl:43 WvTh:44 WvTl:45 WoTh:46 WoTl:47  (96MB)

#define SEQ 2048
#define EMB 1024
#define NH 16
#define HD 64
#define LOG2E 1.44269504088896340736f
#define MU (1u << 20)

typedef short v8s __attribute__((ext_vector_type(8)));
typedef float v4f __attribute__((ext_vector_type(4)));
typedef float v16f __attribute__((ext_vector_type(16)));
typedef unsigned int v4u __attribute__((ext_vector_type(4)));

__device__ __forceinline__ v4f mfma16(v8s a, v8s b, v4f c) {
  return __builtin_amdgcn_mfma_f32_16x16x32_bf16(a, b, c, 0, 0, 0);
}
__device__ __forceinline__ v16f mfma32(v8s a, v8s b, v16f c) {
  return __builtin_amdgcn_mfma_f32_32x32x16_bf16(a, b, c, 0, 0, 0);
}
__device__ __forceinline__ unsigned short bfh(float x) {
  unsigned u = __builtin_bit_cast(unsigned, x);
  return (unsigned short)((u + 0x7FFFu + ((u >> 16) & 1u)) >> 16);
}
__device__ __forceinline__ float bff(unsigned short h) {
  unsigned u = (unsigned)h << 16;
  return __builtin_bit_cast(float, u);
}
__device__ __forceinline__ int imin(int a, int b) { return a < b ? a : b; }

__device__ __forceinline__ void split2(float a, float b, unsigned& uh, unsigned& ul) {
  unsigned h;
  asm("v_cvt_pk_bf16_f32 %0, %1, %2" : "=v"(h) : "v"(a), "v"(b));
  const float ra = __builtin_bit_cast(float, h << 16);
  const float rb = __builtin_bit_cast(float, h & 0xFFFF0000u);
  unsigned lo;
  const float la = a - ra, lb = b - rb;
  asm("v_cvt_pk_bf16_f32 %0, %1, %2" : "=v"(lo) : "v"(la), "v"(lb));
  uh = h;
  ul = lo;
}

// ---------------- prepass: hs split + W transpose/split -----------------------
__global__ __launch_bounds__(256) void prep_kernel(
    const float* __restrict__ hs, const float* __restrict__ Wq,
    const float* __restrict__ Wk, const float* __restrict__ Wv,
    const float* __restrict__ Wo, unsigned short* __restrict__ wsu) {
  __shared__ float T[64][68];
  const int t = threadIdx.x;
  const int z = blockIdx.z;
  if (z == 4) {
    unsigned short* ah = wsu + 32u * MU;
    unsigned short* al = wsu + 36u * MU;
    const int base = (blockIdx.y * 16 + blockIdx.x) * 16384 + t * 4;
#pragma unroll
    for (int i = 0; i < 16; ++i) {
      const int idx = base + i * 1024;
      const float4 v = *(const float4*)(hs + idx);
      unsigned h0, l0, h1, l1;
      split2(v.x, v.y, h0, l0);
      split2(v.z, v.w, h1, l1);
      *(uint2*)&ah[idx] = make_uint2(h0, h1);
      *(uint2*)&al[idx] = make_uint2(l0, l1);
    }
    return;
  }
  const float* W = (z == 0) ? Wq : (z == 1) ? Wk : (z == 2) ? Wv : Wo;
  const float s = (z == 0) ? 0.125f * LOG2E : 1.0f;
  unsigned short* WTh = wsu + (size_t)(40u + 2u * z) * MU;
  unsigned short* WTl = WTh + MU;
  const int n0 = blockIdx.x * 64, k0 = blockIdx.y * 64;
  const int r = t >> 2, cs = (t & 3) * 16;
#pragma unroll
  for (int i = 0; i < 4; ++i)
    *(float4*)&T[r][cs + i * 4] =
        *(const float4*)(W + (size_t)(k0 + r) * EMB + n0 + cs + i * 4);
  __syncthreads();
  unsigned short hb[16], lb[16];
#pragma unroll
  for (int i = 0; i < 16; i += 2) {
    const float a = T[cs + i][r] * s, b2 = T[cs + i + 1][r] * s;
    unsigned uh, ul;
    split2(a, b2, uh, ul);
    hb[i] = (unsigned short)(uh & 0xFFFFu);
    hb[i + 1] = (unsigned short)(uh >> 16);
    lb[i] = (unsigned short)(ul & 0xFFFFu);
    lb[i + 1] = (unsigned short)(ul >> 16);
  }
  const size_t go = (size_t)(n0 + r) * EMB + k0 + cs;
  *(v8s*)&WTh[go] = *(v8s*)&hb[0];
  *(v8s*)&WTh[go + 8] = *(v8s*)&hb[8];
  *(v8s*)&WTl[go] = *(v8s*)&lb[0];
  *(v8s*)&WTl[go + 8] = *(v8s*)&lb[8];
}

// ---------------- 128x128 bf16 GEMM body -------------------------------------
struct alignas(16) GemmSmem {
  unsigned short Ah[128][40], Al[128][40], Bh[128][40], Bl[128][40];
};

__device__ __forceinline__ void gemm128_bf(
    const unsigned short* __restrict__ Ah_g, const unsigned short* __restrict__ Al_g,
    const unsigned short* __restrict__ Bh_g, const unsigned short* __restrict__ Bl_g,
    int m0, int n0, GemmSmem& S, v4f acc[4][4]) {
  const int t = threadIdx.x;
  const int l = t & 63, w = t >> 6;
  const int wm = (w >> 1) << 6, wn = (w & 1) << 6;
  const int lg = l >> 4, lc = l & 15;
  const int sr = t >> 2, skc = (t & 3) * 8;
  for (int k0 = 0; k0 < EMB; k0 += 32) {
    __syncthreads();
    {
      const size_t a0 = (size_t)(m0 + sr) * EMB + k0 + skc;
      const size_t a1 = (size_t)(m0 + 64 + sr) * EMB + k0 + skc;
      *(v8s*)&S.Ah[sr][skc] = *(const v8s*)(Ah_g + a0);
      *(v8s*)&S.Ah[64 + sr][skc] = *(const v8s*)(Ah_g + a1);
      *(v8s*)&S.Al[sr][skc] = *(const v8s*)(Al_g + a0);
      *(v8s*)&S.Al[64 + sr][skc] = *(const v8s*)(Al_g + a1);
      const size_t b0 = (size_t)(n0 + sr) * EMB + k0 + skc;
      const size_t b1 = (size_t)(n0 + 64 + sr) * EMB + k0 + skc;
      *(v8s*)&S.Bh[sr][skc] = *(const v8s*)(Bh_g + b0);
      *(v8s*)&S.Bh[64 + sr][skc] = *(const v8s*)(Bh_g + b1);
      *(v8s*)&S.Bl[sr][skc] = *(const v8s*)(Bl_g + b0);
      *(v8s*)&S.Bl[64 + sr][skc] = *(const v8s*)(Bl_g + b1);
    }
    __syncthreads();
    v8s ah[4], al[4], bh[4], bl[4];
#pragma unroll
    for (int r = 0; r < 4; ++r) {
      ah[r] = *(const v8s*)&S.Ah[wm + r * 16 + lc][lg * 8];
      al[r] = *(const v8s*)&S.Al[wm + r * 16 + lc][lg * 8];
      bh[r] = *(const v8s*)&S.Bh[wn + r * 16 + lc][lg * 8];
      bl[r] = *(const v8s*)&S.Bl[wn + r * 16 + lc][lg * 8];
    }
#pragma unroll
    for (int i = 0; i < 4; ++i)
#pragma unroll
      for (int j = 0; j < 4; ++j) {
        acc[i][j] = mfma16(ah[i], bh[j], acc[i][j]);
        acc[i][j] = mfma16(ah[i], bl[j], acc[i][j]);
        acc[i][j] = mfma16(al[i], bh[j], acc[i][j]);
      }
  }
}

// ---------------- kernel: QKV projection (V written transposed) --------------
__global__ __launch_bounds__(256) void qkv_mfma(
    const float* __restrict__ bq, const float* __restrict__ bk,
    const float* __restrict__ bv, unsigned short* __restrict__ wsu) {
  __shared__ GemmSmem S;
  const int mat = blockIdx.y >> 3;
  const int m0 = blockIdx.x << 7, n0 = (blockIdx.y & 7) << 7;
  const unsigned short* Ah_g = wsu + 32u * MU;
  const unsigned short* Al_g = wsu + 36u * MU;
  const unsigned short* Bh_g = wsu + (size_t)(40u + 2u * mat) * MU;
  const unsigned short* Bl_g = Bh_g + MU;
  const float* bias = (mat == 0) ? bq : (mat == 1) ? bk : bv;
  const float bs = (mat == 0) ? 0.125f * LOG2E : 1.0f;
  unsigned short* oh = wsu + (size_t)mat * 8u * MU;  // q:0 k:8 v(t):16
  unsigned short* ol = oh + 4u * MU;

  v4f acc[4][4] = {};
  gemm128_bf(Ah_g, Al_g, Bh_g, Bl_g, m0, n0, S, acc);

  const int t = threadIdx.x, l = t & 63, w = t >> 6;
  const int wm = (w >> 1) << 6, wn = (w & 1) << 6, lg = l >> 4, lc = l & 15;
  if (mat < 2) {
#pragma unroll
    for (int i = 0; i < 4; ++i)
#pragma unroll
      for (int j = 0; j < 4; ++j)
#pragma unroll
        for (int jr = 0; jr < 4; ++jr) {
          const int r = m0 + wm + i * 16 + lg * 4 + jr;  // b*2048 + s
          const int cm = n0 + wn + j * 16 + lc;          // h*64 + d
          const float val = acc[i][j][jr] + bias[cm] * bs;
          const unsigned short h = bfh(val);
          const unsigned short lo = bfh(val - bff(h));
          const size_t idx =
              (((size_t)((r >> 11) * NH + (cm >> 6)) * SEQ) + (r & 2047)) * HD +
              (cm & 63);
          oh[idx] = h;
          ol[idx] = lo;
        }
  } else {  // V: write transposed [bh][d][s] (feeds PV directly)
#pragma unroll
    for (int i = 0; i < 4; ++i)
#pragma unroll
      for (int j = 0; j < 4; ++j) {
        const int r0 = m0 + wm + i * 16 + lg * 4;
        const int b = r0 >> 11, s0 = r0 & 2047;
        const int cm = n0 + wn + j * 16 + lc;
        const int h = cm >> 6, d = cm & 63;
        unsigned short hb[4], lb[4];
#pragma unroll
        for (int jr = 0; jr < 4; ++jr) {
          const float val = acc[i][j][jr] + bias[cm];
          hb[jr] = bfh(val);
          lb[jr] = bfh(val - bff(hb[jr]));
        }
        const size_t idx = (((size_t)(b * NH + h)) * HD + d) * SEQ + s0;
        *(uint2*)&oh[idx] = *(uint2*)hb;
        *(uint2*)&ol[idx] = *(uint2*)lb;
      }
  }
}

// ---------------- kernel: flash attention ------------------------------------
struct alignas(16) AttnSmem {
  unsigned short Kh[2][64][64], Kl[2][64][64];
  unsigned short VTh[2][64][64], VTl[2][64][64];
  float bias8[32];
};

struct Stg {
  v8s v0, v1, v2, v3, v4, v5, v6, v7;
};

__device__ __forceinline__ Stg load_tile(const unsigned short* __restrict__ kh,
                                         const unsigned short* __restrict__ kl,
                                         const unsigned short* __restrict__ vth,
                                         const unsigned short* __restrict__ vtl,
                                         int bh, int kv0, int srow, int scol) {
  Stg s;
  const size_t gk = ((size_t)bh * SEQ + kv0 + srow) * HD + scol;
  const size_t gv = ((size_t)bh * HD + srow) * SEQ + kv0 + scol;
  s.v0 = *(const v8s*)(kh + gk);
  s.v1 = *(const v8s*)(kh + gk + 8);
  s.v2 = *(const v8s*)(kl + gk);
  s.v3 = *(const v8s*)(kl + gk + 8);
  s.v4 = *(const v8s*)(vth + gv);
  s.v5 = *(const v8s*)(vth + gv + 8);
  s.v6 = *(const v8s*)(vtl + gv);
  s.v7 = *(const v8s*)(vtl + gv + 8);
  return s;
}

// rebuild PV B-fragment from S^T C-layout pairs via half swap
__device__ __forceinline__ v8s pfrag(unsigned a0, unsigned a1, unsigned a2,
                                     unsigned a3, int h5) {
  const unsigned sa = (unsigned)__shfl_xor((int)(h5 ? a0 : a2), 32, 64);
  const unsigned sb = (unsigned)__shfl_xor((int)(h5 ? a1 : a3), 32, 64);
  v4u r;
  r[0] = h5 ? sa : a0;
  r[1] = h5 ? sb : a1;
  r[2] = h5 ? a2 : sa;
  r[3] = h5 ? a3 : sb;
  return __builtin_bit_cast(v8s, r);
}

__global__ __launch_bounds__(256, 2) void attn_mfma(
    const float* __restrict__ rel_bias, unsigned short* __restrict__ wsu) {
  __shared__ AttnSmem S;
  const int t = threadIdx.x;
  const int bid = blockIdx.x;
  const int nid = (bid & 7) * 64 + (bid >> 3);  // XCD swizzle
  const int qt = nid & 15, bh = nid >> 4;
  const int hh = bh & 15, b = bh >> 4;
  const int w = t >> 6, l = t & 63;
  const int lq = l & 31, h5 = l >> 5;
  const int qbase = qt * 128 + w * 32;

  const unsigned short* qh = wsu;
  const unsigned short* ql = wsu + 4u * MU;
  const unsigned short* kh = wsu + 8u * MU;
  const unsigned short* kl = wsu + 12u * MU;
  const unsigned short* vth = wsu + 16u * MU;
  const unsigned short* vtl = wsu + 20u * MU;
  unsigned short* ctxh = wsu + 24u * MU;
  unsigned short* ctxl = wsu + 28u * MU;

  if (t < 32) S.bias8[t] = rel_bias[t * NH + hh] * 8.0f * LOG2E;

  v8s qfh[4], qfl[4];
  const size_t qg = ((size_t)bh * SEQ + qbase + lq) * HD;
#pragma unroll
  for (int dc = 0; dc < 4; ++dc) {
    qfh[dc] = *(const v8s*)(qh + qg + dc * 16 + h5 * 8);
    qfl[dc] = *(const v8s*)(ql + qg + dc * 16 + h5 * 8);
  }

  float m_run = -1e30f, l_run = 0.0f;
  v16f acc[2] = {};

  const int srow = t >> 2;         // 0..63
  const int scol = (t & 3) << 4;   // ushort col {0,16,32,48}
  const int wg0 = ((scol >> 3) ^ (srow & 7)) << 3;        // swizzled write cols
  const int wg1 = (((scol >> 3) + 1) ^ (srow & 7)) << 3;

  Stg stg = load_tile(kh, kl, vth, vtl, bh, 0, srow, scol);

  for (int kt = 0; kt < SEQ / 64; ++kt) {
    const int buf = kt & 1;
    const int kv0 = kt << 6;
    // write tile kt (staged in regs), issue loads for kt+1
    *(v8s*)&S.Kh[buf][srow][wg0] = stg.v0;
    *(v8s*)&S.Kh[buf][srow][wg1] = stg.v1;
    *(v8s*)&S.Kl[buf][srow][wg0] = stg.v2;
    *(v8s*)&S.Kl[buf][srow][wg1] = stg.v3;
    *(v8s*)&S.VTh[buf][srow][wg0] = stg.v4;
    *(v8s*)&S.VTh[buf][srow][wg1] = stg.v5;
    *(v8s*)&S.VTl[buf][srow][wg0] = stg.v6;
    *(v8s*)&S.VTl[buf][srow][wg1] = stg.v7;
    if (kt < SEQ / 64 - 1)
      stg = load_tile(kh, kl, vth, vtl, bh, kv0 + 64, srow, scol);
    __syncthreads();

    // ---- QK^T swapped (3-pass): sc[kb] = K[kb] * Q -> S^T fragment ----
    v16f sc[2] = {};
    __builtin_amdgcn_s_setprio(1);
#pragma unroll
    for (int kb = 0; kb < 2; ++kb)
#pragma unroll
      for (int dc = 0; dc < 4; ++dc) {
        const int cswz = (((dc << 1) + h5) ^ (lq & 7)) << 3;
        const v8s kfh = *(const v8s*)&S.Kh[buf][kb * 32 + lq][cswz];
        const v8s kfl = *(const v8s*)&S.Kl[buf][kb * 32 + lq][cswz];
        sc[kb] = mfma32(kfh, qfh[dc], sc[kb]);
        sc[kb] = mfma32(kfh, qfl[dc], sc[kb]);
        sc[kb] = mfma32(kfl, qfh[dc], sc[kb]);
      }
    __builtin_amdgcn_s_setprio(0);

    // ---- rel-pos bias (log2 domain), per 32-kv subtile ----
#pragma unroll
    for (int kb = 0; kb < 2; ++kb) {
      const int dq = qbase - (kv0 + kb * 32);
      if (dq + 31 <= 0) {
        const float bb = S.bias8[0];
#pragma unroll
        for (int r = 0; r < 16; ++r) sc[kb][r] += bb;
      } else if (dq >= 90) {
        const float bb = S.bias8[31];
#pragma unroll
        for (int r = 0; r < 16; ++r) sc[kb][r] += bb;
      } else {
#pragma unroll
        for (int r = 0; r < 16; ++r) {
          const int krow = (r & 3) + 8 * (r >> 2) + 4 * h5;
          int rp = (qbase + lq) - (kv0 + kb * 32 + krow);
          rp = rp > 0 ? rp : 0;
          const int bu =
              rp < 16 ? rp
                      : imin(16 + (int)(8.0f * __log2f((float)rp * 0.0625f)), 31);
          sc[kb][r] += S.bias8[bu];
        }
      }
    }

    // ---- online softmax with defer-max (THR=8 in log2 domain) ----
    float mt = sc[0][0];
#pragma unroll
    for (int r = 1; r < 16; ++r) mt = fmaxf(mt, sc[0][r]);
#pragma unroll
    for (int r = 0; r < 16; ++r) mt = fmaxf(mt, sc[1][r]);
    mt = fmaxf(mt, __shfl_xor(mt, 32, 64));
    if (__all(mt <= m_run + 8.0f) == 0) {
      const float mn = fmaxf(m_run, mt);
      const float fac = exp2f(m_run - mn);
      l_run *= fac;
#pragma unroll
      for (int r = 0; r < 16; ++r) {
        acc[0][r] *= fac;
        acc[1][r] *= fac;
      }
      m_run = mn;
    }
    unsigned pk[16];
    float rs = 0.0f;
#pragma unroll
    for (int i = 0; i < 16; ++i) {
      const float p0 = exp2f(sc[i >> 3][(2 * i) & 15] - m_run);
      const float p1 = exp2f(sc[i >> 3][(2 * i + 1) & 15] - m_run);
      rs += p0 + p1;
      asm("v_cvt_pk_bf16_f32 %0, %1, %2" : "=v"(pk[i]) : "v"(p0), "v"(p1));
    }
    rs += __shfl_xor(rs, 32, 64);
    l_run += rs;

    // ---- PV (2-pass: Ph*(Vh+Vl)), O^T accumulate ----
    __builtin_amdgcn_s_setprio(1);
#pragma unroll
    for (int ks = 0; ks < 4; ++ks) {
      const v8s pb = pfrag(pk[4 * ks], pk[4 * ks + 1], pk[4 * ks + 2],
                           pk[4 * ks + 3], h5);
      const int cswz = (((ks << 1) + h5) ^ (lq & 7)) << 3;
#pragma unroll
      for (int db = 0; db < 2; ++db) {
        const v8s vfh = *(const v8s*)&S.VTh[buf][db * 32 + lq][cswz];
        const v8s vfl = *(const v8s*)&S.VTl[buf][db * 32 + lq][cswz];
        acc[db] = mfma32(vfh, pb, acc[db]);
        acc[db] = mfma32(vfl, pb, acc[db]);
      }
    }
    __builtin_amdgcn_s_setprio(0);
  }

  // epilogue: normalize, split to ctx hi/lo bf16
  const float inv = 1.0f / l_run;
  const size_t rowb = ((size_t)b * SEQ + qbase + lq) * EMB + hh * HD;
#pragma unroll
  for (int db = 0; db < 2; ++db)
#pragma unroll
    for (int i = 0; i < 8; ++i) {
      const float a = acc[db][2 * i] * inv, c = acc[db][2 * i + 1] * inv;
      unsigned uh, ul;
      split2(a, c, uh, ul);
      const int d0 = db * 32 + 8 * (i >> 1) + 4 * h5 + 2 * (i & 1);
      *(unsigned*)&ctxh[rowb + d0] = uh;
      *(unsigned*)&ctxl[rowb + d0] = ul;
    }
}

// ---------------- kernel: output projection ----------------------------------
__global__ __launch_bounds__(256) void out_mfma(
    const float* __restrict__ bo, float* __restrict__ out,
    unsigned short* __restrict__ wsu) {
  __shared__ GemmSmem S;
  const int m0 = blockIdx.x << 7, n0 = blockIdx.y << 7;
  const unsigned short* Ah_g = wsu + 24u * MU;
  const unsigned short* Al_g = wsu + 28u * MU;
  const unsigned short* Bh_g = wsu + 46u * MU;
  const unsigned short* Bl_g = wsu + 47u * MU;
  v4f acc[4][4] = {};
  gemm128_bf(Ah_g, Al_g, Bh_g, Bl_g, m0, n0, S, acc);
  const int t = threadIdx.x, l = t & 63, w = t >> 6;
  const int wm = (w >> 1) << 6, wn = (w & 1) << 6, lg = l >> 4, lc = l & 15;
#pragma unroll
  for (int i = 0; i < 4; ++i)
#pragma unroll
    for (int j = 0; j < 4; ++j)
#pragma unroll
      for (int jr = 0; jr < 4; ++jr) {
        const int r = m0 + wm + i * 16 + lg * 4 + jr;
        const int c = n0 + wn + j * 16 + lc;
        out[(size_t)r * EMB + c] = acc[i][j][jr] + bo[c];
      }
}

extern "C" void kernel_launch(void* const* d_in, const int* in_sizes, int n_in,
                              void* d_out, int out_size, void* d_ws, size_t ws_size,
                              hipStream_t stream) {
  const float* hs = (const float*)d_in[0];
  const float* Wq = (const float*)d_in[1];
  const float* bq = (const float*)d_in[2];
  const float* Wk = (const float*)d_in[3];
  const float* bk = (const float*)d_in[4];
  const float* Wv = (const float*)d_in[5];
  const float* bv = (const float*)d_in[6];
  const float* Wo = (const float*)d_in[7];
  const float* bo = (const float*)d_in[8];
  const float* rb = (const float*)d_in[9];
  unsigned short* wsu = (unsigned short*)d_ws;

  hipLaunchKernelGGL(prep_kernel, dim3(16, 16, 5), dim3(256), 0, stream,
                     hs, Wq, Wk, Wv, Wo, wsu);
  hipLaunchKernelGGL(qkv_mfma, dim3(32, 24), dim3(256), 0, stream, bq, bk, bv, wsu);
  hipLaunchKernelGGL(attn_mfma, dim3(512), dim3(256), 0, stream, rb, wsu);
  hipLaunchKernelGGL(out_mfma, dim3(32, 8), dim3(256), 0, stream, bo, (float*)d_out, wsu);
}

// Round 6
// 298.560 us; speedup vs baseline: 4.1389x; 1.2584x over previous
//
#include <hip/hip_runtime.h>
#include <math.h>

// Round 6: gload_lds GEMMs (2-pass split, A-hi-only) + KV-split flash attention
// with pre-swizzled K/VT layouts (linear DMA staging) + merge kernel.
// ws layout (MU = 1M ushorts = 2MB):
//  qh:0 ql:4 kh:8(swz,hi only) vth:16(swz) vtl:20(swz) O0:24 O1:28 hsh:32
//  stats:36(1MB f32x2) WqTh:40 WqTl:41 WkTh:42 WkTl:43 WvTh:44 WvTl:45
//  WoTh:46 WoTl:47   (96MB total)

#define SEQ 2048
#define EMB 1024
#define NH 16
#define HD 64
#define LOG2E 1.44269504088896340736f
#define MU (1u << 20)

typedef short v8s __attribute__((ext_vector_type(8)));
typedef float v4f __attribute__((ext_vector_type(4)));
typedef float v16f __attribute__((ext_vector_type(16)));
typedef unsigned int v4u __attribute__((ext_vector_type(4)));

__device__ __forceinline__ v4f mfma16(v8s a, v8s b, v4f c) {
  return __builtin_amdgcn_mfma_f32_16x16x32_bf16(a, b, c, 0, 0, 0);
}
__device__ __forceinline__ v16f mfma32(v8s a, v8s b, v16f c) {
  return __builtin_amdgcn_mfma_f32_32x32x16_bf16(a, b, c, 0, 0, 0);
}
__device__ __forceinline__ unsigned short bfh(float x) {
  unsigned u = __builtin_bit_cast(unsigned, x);
  return (unsigned short)((u + 0x7FFFu + ((u >> 16) & 1u)) >> 16);
}
__device__ __forceinline__ float bff(unsigned short h) {
  unsigned u = (unsigned)h << 16;
  return __builtin_bit_cast(float, u);
}
__device__ __forceinline__ int imin(int a, int b) { return a < b ? a : b; }
__device__ __forceinline__ unsigned pk2(float a, float b) {
  unsigned h;
  asm("v_cvt_pk_bf16_f32 %0, %1, %2" : "=v"(h) : "v"(a), "v"(b));
  return h;
}
__device__ __forceinline__ void split2(float a, float b, unsigned& uh, unsigned& ul) {
  const unsigned h = pk2(a, b);
  const float ra = __builtin_bit_cast(float, h << 16);
  const float rb = __builtin_bit_cast(float, h & 0xFFFF0000u);
  uh = h;
  ul = pk2(a - ra, b - rb);
}
typedef const __attribute__((address_space(1))) unsigned char* gp_t;
typedef __attribute__((address_space(3))) unsigned char* lp_t;
__device__ __forceinline__ void gload16(const void* g, void* l) {
  __builtin_amdgcn_global_load_lds((gp_t)g, (lp_t)l, 16, 0, 0);
}

// ---------------- prepass: hs hi-split + W transpose/split -------------------
__global__ __launch_bounds__(256) void prep_kernel(
    const float* __restrict__ hs, const float* __restrict__ Wq,
    const float* __restrict__ Wk, const float* __restrict__ Wv,
    const float* __restrict__ Wo, unsigned short* __restrict__ wsu) {
  __shared__ float T[64][68];
  const int t = threadIdx.x;
  const int z = blockIdx.z;
  if (z == 4) {  // hs -> bf16 hi only
    unsigned short* ah = wsu + 32u * MU;
    const int base = (blockIdx.y * 16 + blockIdx.x) * 16384 + t * 4;
#pragma unroll
    for (int i = 0; i < 16; ++i) {
      const int idx = base + i * 1024;
      const float4 v = *(const float4*)(hs + idx);
      *(uint2*)&ah[idx] = make_uint2(pk2(v.x, v.y), pk2(v.z, v.w));
    }
    return;
  }
  const float* W = (z == 0) ? Wq : (z == 1) ? Wk : (z == 2) ? Wv : Wo;
  const float s = (z == 0) ? 0.125f * LOG2E : 1.0f;
  unsigned short* WTh = wsu + (size_t)(40u + 2u * z) * MU;
  unsigned short* WTl = WTh + MU;
  const int n0 = blockIdx.x * 64, k0 = blockIdx.y * 64;
  const int r = t >> 2, cs = (t & 3) * 16;
#pragma unroll
  for (int i = 0; i < 4; ++i)
    *(float4*)&T[r][cs + i * 4] =
        *(const float4*)(W + (size_t)(k0 + r) * EMB + n0 + cs + i * 4);
  __syncthreads();
  unsigned short hb[16], lb[16];
#pragma unroll
  for (int i = 0; i < 16; i += 2) {
    unsigned uh, ul;
    split2(T[cs + i][r] * s, T[cs + i + 1][r] * s, uh, ul);
    hb[i] = (unsigned short)(uh & 0xFFFFu);
    hb[i + 1] = (unsigned short)(uh >> 16);
    lb[i] = (unsigned short)(ul & 0xFFFFu);
    lb[i + 1] = (unsigned short)(ul >> 16);
  }
  const size_t go = (size_t)(n0 + r) * EMB + k0 + cs;
  *(v8s*)&WTh[go] = *(v8s*)&hb[0];
  *(v8s*)&WTh[go + 8] = *(v8s*)&hb[8];
  *(v8s*)&WTl[go] = *(v8s*)&lb[0];
  *(v8s*)&WTl[go + 8] = *(v8s*)&lb[8];
}

// ------------- 128x128 GEMM, 2-pass (Ah*Bh + Ah*Bl), gload_lds staging -------
struct alignas(16) G2Smem {
  unsigned short Ah[128][32], Bh[128][32], Bl[128][32];  // 24KB
};

__device__ __forceinline__ void gemm128_2p(
    const unsigned short* __restrict__ Ah_g,
    const unsigned short* __restrict__ Bh_g,
    const unsigned short* __restrict__ Bl_g,
    int m0, int n0, G2Smem& S, v4f acc[4][4]) {
  const int t = threadIdx.x;
  const int l = t & 63, w = t >> 6;
  const int wm = (w >> 1) << 6, wn = (w & 1) << 6;
  const int lg = l >> 4, lc = l & 15;
  const int r0 = t >> 2;                    // deposit row (and +64)
  const int gl = (t & 3) ^ ((r0 >> 1) & 3); // swizzled source granule
  unsigned short* lba = &S.Ah[0][0] + w * 512;
  unsigned short* lbb = &S.Bh[0][0] + w * 512;
  unsigned short* lbl = &S.Bl[0][0] + w * 512;
  for (int k0 = 0; k0 < EMB; k0 += 32) {
    __syncthreads();
    {
      const size_t sa0 = (size_t)(m0 + r0) * EMB + k0 + gl * 8;
      const size_t sb0 = (size_t)(n0 + r0) * EMB + k0 + gl * 8;
      gload16(Ah_g + sa0, lba);
      gload16(Ah_g + sa0 + (size_t)64 * EMB, lba + 2048);
      gload16(Bh_g + sb0, lbb);
      gload16(Bh_g + sb0 + (size_t)64 * EMB, lbb + 2048);
      gload16(Bl_g + sb0, lbl);
      gload16(Bl_g + sb0 + (size_t)64 * EMB, lbl + 2048);
    }
    asm volatile("s_waitcnt vmcnt(0)" ::: "memory");
    __syncthreads();
    v8s ah[4], bh[4], bl[4];
#pragma unroll
    for (int r = 0; r < 4; ++r) {
      const int ra = wm + r * 16 + lc;
      ah[r] = *(const v8s*)&S.Ah[ra][(lg ^ ((ra >> 1) & 3)) * 8];
      const int rb = wn + r * 16 + lc;
      bh[r] = *(const v8s*)&S.Bh[rb][(lg ^ ((rb >> 1) & 3)) * 8];
      bl[r] = *(const v8s*)&S.Bl[rb][(lg ^ ((rb >> 1) & 3)) * 8];
    }
#pragma unroll
    for (int i = 0; i < 4; ++i)
#pragma unroll
      for (int j = 0; j < 4; ++j) {
        acc[i][j] = mfma16(ah[i], bh[j], acc[i][j]);
        acc[i][j] = mfma16(ah[i], bl[j], acc[i][j]);
      }
  }
  __syncthreads();  // LDS safe to reuse
}

// ---------------- kernel: QKV projection -------------------------------------
__global__ __launch_bounds__(256) void qkv_mfma(
    const float* __restrict__ bq, const float* __restrict__ bk,
    const float* __restrict__ bv, unsigned short* __restrict__ wsu) {
  __shared__ G2Smem S;
  const int mat = blockIdx.y >> 3;
  const int m0 = blockIdx.x << 7, n0 = (blockIdx.y & 7) << 7;
  const unsigned short* Ah_g = wsu + 32u * MU;
  const unsigned short* Bh_g = wsu + (size_t)(40u + 2u * mat) * MU;
  const unsigned short* Bl_g = Bh_g + MU;
  const float* bias = (mat == 0) ? bq : (mat == 1) ? bk : bv;
  const float bs = (mat == 0) ? 0.125f * LOG2E : 1.0f;
  unsigned short* oh = wsu + (size_t)mat * 8u * MU;  // q:0 k:8 v(t):16
  unsigned short* ol = oh + 4u * MU;

  v4f acc[4][4] = {};
  gemm128_2p(Ah_g, Bh_g, Bl_g, m0, n0, S, acc);

  const int t = threadIdx.x, l = t & 63, w = t >> 6;
  const int wm = (w >> 1) << 6, wn = (w & 1) << 6, lg = l >> 4, lc = l & 15;
  if (mat == 0) {  // Q: plain [bh][s][d], hi+lo
#pragma unroll
    for (int i = 0; i < 4; ++i)
#pragma unroll
      for (int j = 0; j < 4; ++j)
#pragma unroll
        for (int jr = 0; jr < 4; ++jr) {
          const int r = m0 + wm + i * 16 + lg * 4 + jr;
          const int cm = n0 + wn + j * 16 + lc;
          const float val = acc[i][j][jr] + bias[cm] * bs;
          const unsigned short h = bfh(val);
          const size_t idx = (((size_t)((r >> 11) * NH + (cm >> 6)) * SEQ) +
                              (r & 2047)) * HD + (cm & 63);
          oh[idx] = h;
          ol[idx] = bfh(val - bff(h));
        }
  } else if (mat == 1) {  // K: swizzled granules, hi only
#pragma unroll
    for (int i = 0; i < 4; ++i)
#pragma unroll
      for (int j = 0; j < 4; ++j)
#pragma unroll
        for (int jr = 0; jr < 4; ++jr) {
          const int r = m0 + wm + i * 16 + lg * 4 + jr;
          const int cm = n0 + wn + j * 16 + lc;
          const float val = acc[i][j][jr] + bias[cm];
          const int s = r & 2047, d = cm & 63;
          const size_t idx = (((size_t)((r >> 11) * NH + (cm >> 6)) * SEQ) + s) * HD +
                             ((((d >> 3) ^ (s & 7)) << 3) | (d & 7));
          oh[idx] = bfh(val);
        }
  } else {  // V: transpose via LDS -> [bh][d][s] swizzled, hi+lo
    unsigned short* Traw = &S.Ah[0][0];
    unsigned short (*Th)[136] = (unsigned short(*)[136])Traw;
    unsigned short (*Tl)[136] = (unsigned short(*)[136])(Traw + 32 * 136);
    const int b = m0 >> 11;
    const int s0base = m0 & 2047;
#pragma unroll
    for (int j = 0; j < 4; ++j) {
      __syncthreads();
#pragma unroll
      for (int i = 0; i < 4; ++i)
#pragma unroll
        for (int jr = 0; jr < 4; ++jr) {
          const int cm = n0 + wn + j * 16 + lc;
          const float val = acc[i][j][jr] + bias[cm];
          const unsigned short hi = bfh(val);
          const int trow = (wn >> 2) + lc;
          const int tcol = wm + i * 16 + lg * 4 + jr;
          Th[trow][tcol] = hi;
          Tl[trow][tcol] = bfh(val - bff(hi));
        }
      __syncthreads();
      const int tr = t >> 3, sgc = (t & 7) * 16;
      const int c = n0 + (tr >> 4) * 64 + j * 16 + (tr & 15);
      const int h2 = c >> 6, d = c & 63;
      const int sabs = s0base + sgc;
      const int g0 = (sabs >> 3) & 7;  // even
      const size_t ob = ((size_t)(b * NH + h2) * HD + d) * SEQ + (sabs & ~63);
      const int o0 = (g0 ^ (d & 7)) << 3, o1 = ((g0 + 1) ^ (d & 7)) << 3;
      *(v8s*)&oh[ob + o0] = *(const v8s*)&Th[tr][sgc];
      *(v8s*)&oh[ob + o1] = *(const v8s*)&Th[tr][sgc + 8];
      *(v8s*)&ol[ob + o0] = *(const v8s*)&Tl[tr][sgc];
      *(v8s*)&ol[ob + o1] = *(const v8s*)&Tl[tr][sgc + 8];
    }
  }
}

// ---------------- kernel: flash attention (KV-split 2x) ----------------------
__device__ __forceinline__ v8s pfrag(unsigned a0, unsigned a1, unsigned a2,
                                     unsigned a3, int h5) {
  const unsigned sa = (unsigned)__shfl_xor((int)(h5 ? a0 : a2), 32, 64);
  const unsigned sb = (unsigned)__shfl_xor((int)(h5 ? a1 : a3), 32, 64);
  v4u r;
  r[0] = h5 ? sa : a0;
  r[1] = h5 ? sb : a1;
  r[2] = h5 ? a2 : sa;
  r[3] = h5 ? a3 : sb;
  return __builtin_bit_cast(v8s, r);
}

__global__ __launch_bounds__(256, 3) void attn_mfma(
    const float* __restrict__ rel_bias, unsigned short* __restrict__ wsu) {
  __shared__ struct alignas(16) {
    unsigned short Kh[2][64][64];
    unsigned short VTh[2][64][64];
    unsigned short VTl[2][64][64];
    float bias8[32];
  } S;
  const int t = threadIdx.x;
  const int nid = (blockIdx.x & 7) * 128 + (blockIdx.x >> 3);  // XCD swizzle
  const int half = nid >> 9;
  const int bh = (nid >> 4) & 31;
  const int qt = nid & 15;
  const int hh = bh & 15, b = bh >> 4;
  const int w = t >> 6, l = t & 63;
  const int lq = l & 31, h5 = l >> 5;
  const int qbase = qt * 128 + w * 32;
  const int kvbase = half << 10;

  const unsigned short* qh = wsu;
  const unsigned short* ql = wsu + 4u * MU;
  const unsigned short* kh = wsu + 8u * MU;
  const unsigned short* vth = wsu + 16u * MU;
  const unsigned short* vtl = wsu + 20u * MU;
  unsigned short* od = wsu + (half ? 28u : 24u) * MU;
  float2* stats = (float2*)(wsu + 36u * MU);

  if (t < 32) S.bias8[t] = rel_bias[t * NH + hh] * 8.0f * LOG2E;

  v8s qfh[4], qfl[4];
  const size_t qg = ((size_t)bh * SEQ + qbase + lq) * HD;
#pragma unroll
  for (int dc = 0; dc < 4; ++dc) {
    qfh[dc] = *(const v8s*)(qh + qg + dc * 16 + h5 * 8);
    qfl[dc] = *(const v8s*)(ql + qg + dc * 16 + h5 * 8);
  }

  float m_run = -1e30f, l_run = 0.0f;
  v16f acc[2] = {};

  const int srow = t >> 3, sg = t & 7;
  const size_t kbase_g = ((size_t)bh * SEQ + kvbase) * HD;
  const size_t vbase_g = (size_t)bh * HD * SEQ + kvbase;

  auto stage = [&](int kt, int bufsel) {
    const int kv0 = kt * 64;
    unsigned short* lk = &S.Kh[bufsel][0][0] + w * 512;
    unsigned short* lvh = &S.VTh[bufsel][0][0] + w * 512;
    unsigned short* lvl = &S.VTl[bufsel][0][0] + w * 512;
    gload16(kh + kbase_g + (size_t)(kv0 + srow) * HD + sg * 8, lk);
    gload16(kh + kbase_g + (size_t)(kv0 + srow + 32) * HD + sg * 8, lk + 2048);
    gload16(vth + vbase_g + (size_t)srow * SEQ + kv0 + sg * 8, lvh);
    gload16(vth + vbase_g + (size_t)(srow + 32) * SEQ + kv0 + sg * 8, lvh + 2048);
    gload16(vtl + vbase_g + (size_t)srow * SEQ + kv0 + sg * 8, lvl);
    gload16(vtl + vbase_g + (size_t)(srow + 32) * SEQ + kv0 + sg * 8, lvl + 2048);
  };

  stage(0, 0);
  for (int kt = 0; kt < 16; ++kt) {
    const int buf = kt & 1;
    const int kv0 = kvbase + kt * 64;
    asm volatile("s_waitcnt vmcnt(0)" ::: "memory");
    __syncthreads();
    if (kt < 15) stage(kt + 1, buf ^ 1);

    // ---- QK^T swapped, 2-pass (Kh*Qh + Kh*Ql) ----
    v16f sc[2] = {};
    __builtin_amdgcn_s_setprio(1);
#pragma unroll
    for (int kb = 0; kb < 2; ++kb)
#pragma unroll
      for (int dc = 0; dc < 4; ++dc) {
        const int cswz = (((dc << 1) + h5) ^ (lq & 7)) << 3;
        const v8s kfh = *(const v8s*)&S.Kh[buf][kb * 32 + lq][cswz];
        sc[kb] = mfma32(kfh, qfh[dc], sc[kb]);
        sc[kb] = mfma32(kfh, qfl[dc], sc[kb]);
      }
    __builtin_amdgcn_s_setprio(0);

    // ---- rel-pos bias (log2 domain) ----
#pragma unroll
    for (int kb = 0; kb < 2; ++kb) {
      const int dq = qbase - (kv0 + kb * 32);
      if (dq + 31 <= 0) {
        const float bb = S.bias8[0];
#pragma unroll
        for (int r = 0; r < 16; ++r) sc[kb][r] += bb;
      } else if (dq >= 90) {
        const float bb = S.bias8[31];
#pragma unroll
        for (int r = 0; r < 16; ++r) sc[kb][r] += bb;
      } else {
#pragma unroll
        for (int r = 0; r < 16; ++r) {
          const int krow = (r & 3) + 8 * (r >> 2) + 4 * h5;
          int rp = (qbase + lq) - (kv0 + kb * 32 + krow);
          rp = rp > 0 ? rp : 0;
          const int bu =
              rp < 16 ? rp
                      : imin(16 + (int)(8.0f * __log2f((float)rp * 0.0625f)), 31);
          sc[kb][r] += S.bias8[bu];
        }
      }
    }

    // ---- online softmax, defer-max THR=8 ----
    float mt = sc[0][0];
#pragma unroll
    for (int r = 1; r < 16; ++r) mt = fmaxf(mt, sc[0][r]);
#pragma unroll
    for (int r = 0; r < 16; ++r) mt = fmaxf(mt, sc[1][r]);
    mt = fmaxf(mt, __shfl_xor(mt, 32, 64));
    if (__all(mt <= m_run + 8.0f) == 0) {
      const float mn = fmaxf(m_run, mt);
      const float fac = exp2f(m_run - mn);
      l_run *= fac;
#pragma unroll
      for (int r = 0; r < 16; ++r) {
        acc[0][r] *= fac;
        acc[1][r] *= fac;
      }
      m_run = mn;
    }
    unsigned pk[16];
    float rs = 0.0f;
#pragma unroll
    for (int i = 0; i < 16; ++i) {
      const float p0 = exp2f(sc[i >> 3][(2 * i) & 15] - m_run);
      const float p1 = exp2f(sc[i >> 3][(2 * i + 1) & 15] - m_run);
      rs += p0 + p1;
      pk[i] = pk2(p0, p1);
    }
    rs += __shfl_xor(rs, 32, 64);
    l_run += rs;

    // ---- PV 2-pass (Ph*Vh + Ph*Vl), O^T accumulate ----
    __builtin_amdgcn_s_setprio(1);
#pragma unroll
    for (int ks = 0; ks < 4; ++ks) {
      const v8s pb = pfrag(pk[4 * ks], pk[4 * ks + 1], pk[4 * ks + 2],
                           pk[4 * ks + 3], h5);
      const int cswz = (((ks << 1) + h5) ^ (lq & 7)) << 3;
#pragma unroll
      for (int db = 0; db < 2; ++db) {
        const v8s vfh = *(const v8s*)&S.VTh[buf][db * 32 + lq][cswz];
        const v8s vfl = *(const v8s*)&S.VTl[buf][db * 32 + lq][cswz];
        acc[db] = mfma32(vfh, pb, acc[db]);
        acc[db] = mfma32(vfl, pb, acc[db]);
      }
    }
    __builtin_amdgcn_s_setprio(0);
  }

  // epilogue: normalized partial O (bf16 hi) + stats
  const float inv = 1.0f / l_run;
  const size_t rowb = ((size_t)b * SEQ + qbase + lq) * EMB + hh * HD;
#pragma unroll
  for (int db = 0; db < 2; ++db)
#pragma unroll
    for (int i = 0; i < 8; ++i) {
      const unsigned u = pk2(acc[db][2 * i] * inv, acc[db][2 * i + 1] * inv);
      const int d0 = db * 32 + 8 * (i >> 1) + 4 * h5 + 2 * (i & 1);
      *(unsigned*)&od[rowb + d0] = u;
    }
  if (h5 == 0)
    stats[(size_t)((half << 5) + bh) * SEQ + qbase + lq] =
        make_float2(m_run, l_run);
}

// ---------------- kernel: merge two KV-halves --------------------------------
__global__ __launch_bounds__(256) void merge_kernel(unsigned short* __restrict__ wsu) {
  const int t = threadIdx.x;
  const size_t idx = ((size_t)blockIdx.x * 256 + t) * 16;
  const int row = (int)(idx >> 10);
  const int col = (int)(idx & 1023);
  const int b = row >> 11, s = row & 2047;
  const int bh = b * NH + (col >> 6);
  const float2* st = (const float2*)(wsu + 36u * MU);
  const float2 s0 = st[(size_t)bh * SEQ + s];
  const float2 s1 = st[(size_t)32 * SEQ + (size_t)bh * SEQ + s];
  const float M = fmaxf(s0.x, s1.x);
  const float w0 = s0.y * exp2f(s0.x - M);
  const float w1 = s1.y * exp2f(s1.x - M);
  const float inv = 1.0f / (w0 + w1);
  const float a0 = w0 * inv, a1 = w1 * inv;
  unsigned short* p0 = wsu + 24u * MU + idx;
  const unsigned short* p1 = wsu + 28u * MU + idx;
  const v8s x0a = *(const v8s*)p0, x0b = *(const v8s*)(p0 + 8);
  const v8s x1a = *(const v8s*)p1, x1b = *(const v8s*)(p1 + 8);
  unsigned short o[16];
#pragma unroll
  for (int e = 0; e < 8; ++e) {
    o[e] = bfh(a0 * bff((unsigned short)x0a[e]) + a1 * bff((unsigned short)x1a[e]));
    o[8 + e] =
        bfh(a0 * bff((unsigned short)x0b[e]) + a1 * bff((unsigned short)x1b[e]));
  }
  *(v8s*)p0 = *(const v8s*)&o[0];
  *(v8s*)(p0 + 8) = *(const v8s*)&o[8];
}

// ---------------- kernel: output projection ----------------------------------
__global__ __launch_bounds__(256) void out_mfma(
    const float* __restrict__ bo, float* __restrict__ out,
    unsigned short* __restrict__ wsu) {
  __shared__ G2Smem S;
  const int m0 = blockIdx.x << 7, n0 = blockIdx.y << 7;
  const unsigned short* Ah_g = wsu + 24u * MU;  // merged ctx (bf16 hi)
  const unsigned short* Bh_g = wsu + 46u * MU;
  const unsigned short* Bl_g = wsu + 47u * MU;
  v4f acc[4][4] = {};
  gemm128_2p(Ah_g, Bh_g, Bl_g, m0, n0, S, acc);
  const int t = threadIdx.x, l = t & 63, w = t >> 6;
  const int wm = (w >> 1) << 6, wn = (w & 1) << 6, lg = l >> 4, lc = l & 15;
#pragma unroll
  for (int i = 0; i < 4; ++i)
#pragma unroll
    for (int j = 0; j < 4; ++j)
#pragma unroll
      for (int jr = 0; jr < 4; ++jr) {
        const int r = m0 + wm + i * 16 + lg * 4 + jr;
        const int c = n0 + wn + j * 16 + lc;
        out[(size_t)r * EMB + c] = acc[i][j][jr] + bo[c];
      }
}

extern "C" void kernel_launch(void* const* d_in, const int* in_sizes, int n_in,
                              void* d_out, int out_size, void* d_ws, size_t ws_size,
                              hipStream_t stream) {
  const float* hs = (const float*)d_in[0];
  const float* Wq = (const float*)d_in[1];
  const float* bq = (const float*)d_in[2];
  const float* Wk = (const float*)d_in[3];
  const float* bk = (const float*)d_in[4];
  const float* Wv = (const float*)d_in[5];
  const float* bv = (const float*)d_in[6];
  const float* Wo = (const float*)d_in[7];
  const float* bo = (const float*)d_in[8];
  const float* rb = (const float*)d_in[9];
  unsigned short* wsu = (unsigned short*)d_ws;

  hipLaunchKernelGGL(prep_kernel, dim3(16, 16, 5), dim3(256), 0, stream,
                     hs, Wq, Wk, Wv, Wo, wsu);
  hipLaunchKernelGGL(qkv_mfma, dim3(32, 24), dim3(256), 0, stream, bq, bk, bv, wsu);
  hipLaunchKernelGGL(attn_mfma, dim3(1024), dim3(256), 0, stream, rb, wsu);
  hipLaunchKernelGGL(merge_kernel, dim3(1024), dim3(256), 0, stream, wsu);
  hipLaunchKernelGGL(out_mfma, dim3(32, 8), dim3(256), 0, stream, bo, (float*)d_out, wsu);
}